// Round 10
// baseline (279.967 us; speedup 1.0000x reference)
//
#include <hip/hip_runtime.h>
#include <hip/hip_bf16.h>
#include <stdint.h>

#define NB 4096
#define NCOL 100
#define NCOND 64
#define NTOTAL 6400
#define NRODT 1600
#define NEST 160
#define NFOR 100
#define NHID 128
#define NCLS 10
#define GEPS 1e-5f

typedef __attribute__((ext_vector_type(8))) short short8;
typedef __attribute__((ext_vector_type(4))) float floatx4;

// round-half-up f32->bf16: 2 VALU ops; tie-only difference vs RNE
__device__ __forceinline__ unsigned f2bfu(float x) {
  union { float f; unsigned u; } v; v.f = x;
  return (v.u + 0x8000u) >> 16;
}
__device__ __forceinline__ float bf2f(unsigned short u) {
  union { unsigned u; float f; } v; v.u = ((unsigned)u) << 16;
  return v.f;
}

// all-reduce sum over the 16-lane DPP row -- VALU pipe, no LDS.
__device__ __forceinline__ float rowsum16(float v) {
  union { float f; int i; } a, t;
  a.f = v;
  t.i = __builtin_amdgcn_update_dpp(0, a.i, 0x128, 0xf, 0xf, true); a.f += t.f; // ror:8
  t.i = __builtin_amdgcn_update_dpp(0, a.i, 0x124, 0xf, 0xf, true); a.f += t.f; // ror:4
  t.i = __builtin_amdgcn_update_dpp(0, a.i, 0x122, 0xf, 0xf, true); a.f += t.f; // ror:2
  t.i = __builtin_amdgcn_update_dpp(0, a.i, 0x121, 0xf, 0xf, true); a.f += t.f; // ror:1
  return a.f;
}

// broadcast the value of each 16-lane group's leader (lane & 0x30) to the
// whole group: ds_swizzle BitMode, and_mask=0x10 (keeps bit4 within 32-half).
__device__ __forceinline__ float bcast16(float v) {
  union { float f; int i; } a; a.f = v;
  a.i = __builtin_amdgcn_ds_swizzle(a.i, 0x0010);
  return a.f;
}

// ---------------------------------------------------------------------------
// K01: merged prep kernel (single launch). Unchanged (proven).
//  blocks [0,1600)    : k1 -- ConditionGeneration+perm+phi_2 -> exp(w)^T bf16
//  blocks [1600,1702) : k0 -- fragment-pack Bf / W1f / W2f (identity k-map)
//  blocks [1702,1705) : zero d_out
// ---------------------------------------------------------------------------
__global__ __launch_bounds__(256) void k01_prep(
    const float* __restrict__ x, const float* __restrict__ w1,
    const float* __restrict__ b1, const int* __restrict__ perm,
    const float* __restrict__ gn1w, const float* __restrict__ gn1b,
    const float* __restrict__ c2w, const float* __restrict__ c2b,
    const float* __restrict__ gn2w, const float* __restrict__ gn2b,
    const float* __restrict__ c3w, const float* __restrict__ c3b,
    const float* __restrict__ E, const int* __restrict__ swr,
    const float* __restrict__ fc1w, const float* __restrict__ fc2w,
    unsigned short* __restrict__ wT,
    unsigned short* __restrict__ Bf, unsigned short* __restrict__ W1f,
    unsigned short* __restrict__ W2f, float* __restrict__ out)
{
  __shared__ float xl[64 * NCOL];          // k1 path only (25.6 KB)
  __shared__ int ridx[NEST];               // k0 path only
  const int tid = threadIdx.x;
  const int blk = blockIdx.x;

  if (blk < 1600) {
    // ---------------- k1: phi_2 logits -> exp -> bf16, transposed ----------
    const int b0 = (blk & 63) * 64;
    const int g  = (blk >> 6) * 64 + (tid >> 2);
    const int i4 = tid & 3;
    for (int i = tid; i < 64 * NCOL; i += 256)
      xl[i] = x[(size_t)b0 * NCOL + i];
    __syncthreads();

    const int4 p4 = *(const int4*)(perm + 4 * g);
    const int pv[4] = {p4.x, p4.y, p4.z, p4.w};
    float w1v[4], b1v[4];
    int pc[4];
#pragma unroll
    for (int i = 0; i < 4; i++) {
      unsigned p = (unsigned)pv[i];
      unsigned j = p / 100u;
      unsigned cc = p - j * 100u;
      pc[i] = (int)cc;
      w1v[i] = w1[cc * NCOND + j];
      b1v[i] = b1[cc * NCOND + j];
    }
    const float4 g1w = *(const float4*)(gn1w + 4 * g);
    const float4 g1b = *(const float4*)(gn1b + 4 * g);
    const float4 cw0 = *(const float4*)(c2w + 16 * g);
    const float4 cw1 = *(const float4*)(c2w + 16 * g + 4);
    const float4 cw2 = *(const float4*)(c2w + 16 * g + 8);
    const float4 cw3 = *(const float4*)(c2w + 16 * g + 12);
    const float4 cbv = *(const float4*)(c2b + 4 * g);
    const float4 g2w = *(const float4*)(gn2w + 4 * g);
    const float4 g2b = *(const float4*)(gn2b + 4 * g);
    const float4 c3v = *(const float4*)(c3w + 4 * g);
    const float c3bv = c3b[g];

    for (int k = 0; k < 4; k++) {
      float v4[4];
#pragma unroll
      for (int j = 0; j < 4; j++) {
        const int bb = k * 16 + i4 * 4 + j;
        float O[4];
#pragma unroll
        for (int i = 0; i < 4; i++) {
          float a = xl[bb * NCOL + pc[i]] * w1v[i] + b1v[i];
          O[i] = 1.0f / (1.0f + __expf(-a));
        }
        float mu = 0.25f * (O[0] + O[1] + O[2] + O[3]);
        float d[4], var = 0.f;
#pragma unroll
        for (int i = 0; i < 4; i++) { d[i] = O[i] - mu; var += d[i] * d[i]; }
        float rs = rsqrtf(0.25f * var + GEPS);
        float xn0 = d[0] * rs * g1w.x + g1b.x;
        float xn1 = d[1] * rs * g1w.y + g1b.y;
        float xn2 = d[2] * rs * g1w.z + g1b.z;
        float xn3 = d[3] * rs * g1w.w + g1b.w;
        float h[4];
        h[0] = xn0*cw0.x + xn1*cw1.x + xn2*cw2.x + xn3*cw3.x + cbv.x;
        h[1] = xn0*cw0.y + xn1*cw1.y + xn2*cw2.y + xn3*cw3.y + cbv.y;
        h[2] = xn0*cw0.z + xn1*cw1.z + xn2*cw2.z + xn3*cw3.z + cbv.z;
        h[3] = xn0*cw0.w + xn1*cw1.w + xn2*cw2.w + xn3*cw3.w + cbv.w;
#pragma unroll
        for (int i = 0; i < 4; i++) h[i] = fmaxf(h[i], 0.f);
        float mu2 = 0.25f * (h[0] + h[1] + h[2] + h[3]);
        float e[4], var2 = 0.f;
#pragma unroll
        for (int i = 0; i < 4; i++) { e[i] = h[i] - mu2; var2 += e[i] * e[i]; }
        float rs2 = rsqrtf(0.25f * var2 + GEPS);
        float hn0 = e[0] * rs2 * g2w.x + g2b.x;
        float hn1 = e[1] * rs2 * g2w.y + g2b.y;
        float hn2 = e[2] * rs2 * g2w.z + g2b.z;
        float hn3 = e[3] * rs2 * g2w.w + g2b.w;
        v4[j] = hn0*c3v.x + hn1*c3v.y + hn2*c3v.z + hn3*c3v.w + c3bv;
      }
      // store exp(logit): k3's softmax numerator, once per unique (g,b)
      uint2 pk;
      pk.x = f2bfu(__expf(v4[0])) | (f2bfu(__expf(v4[1])) << 16);
      pk.y = f2bfu(__expf(v4[2])) | (f2bfu(__expf(v4[3])) << 16);
      *(uint2*)(wT + (size_t)g * NB + b0 + k * 16 + i4 * 4) = pk;
    }
  } else if (blk < 1600 + NFOR) {
    // ---------------- k0: Bf fragment pack ----------------
    const int fblk = blk - 1600;
    if (tid < NEST) ridx[tid] = swr[fblk * NEST + tid];
    __syncthreads();
    for (int m = tid; m < 2560; m += 256) {        // m = (n*5+kc)*64 + lane
      int lane = m & 63, rest = m >> 6;
      int kc = rest % 5, n = rest / 5;
      int q = lane >> 4, c = lane & 15;
      int e0 = kc * 32 + q * 8;
      int h = n * 16 + c;
      union { unsigned short v[8]; uint4 u; } t;
#pragma unroll
      for (int j = 0; j < 8; j++)
        t.v[j] = (unsigned short)f2bfu(E[(size_t)ridx[e0 + j] * NHID + h]);
      *(uint4*)(Bf + (size_t)fblk * 20480 + (size_t)m * 8) = t.u;
    }
  } else if (blk == 1600 + NFOR) {
    // ---------------- k0: W1f (identity k-map) ----------------
    for (int m = tid; m < 2048; m += 256) {        // m = (n*4+kc)*64 + lane
      int lane = m & 63, rest = m >> 6;
      int kc = rest & 3, n = rest >> 2;
      int q = lane >> 4, c = lane & 15;
      int k0 = kc * 32 + q * 8;
      int o = n * 16 + c;
      union { unsigned short v[8]; uint4 u; } t;
#pragma unroll
      for (int j = 0; j < 8; j++)
        t.v[j] = (unsigned short)f2bfu(fc1w[(size_t)(k0 + j) * NHID + o]);
      *(uint4*)(W1f + (size_t)m * 8) = t.u;
    }
  } else if (blk == 1601 + NFOR) {
    // ---------------- k0: W2f (identity k-map) ----------------
    for (int m = tid; m < 256; m += 256) {         // m = kc*64 + lane
      int lane = m & 63, kc = m >> 6;
      int q = lane >> 4, c = lane & 15;
      int k0 = kc * 32 + q * 8;
      union { unsigned short v[8]; uint4 u; } t;
#pragma unroll
      for (int j = 0; j < 8; j++)
        t.v[j] = (unsigned short)f2bfu(c < NCLS ? fc2w[(size_t)(k0 + j) * NCLS + c] : 0.f);
      *(uint4*)(W2f + (size_t)m * 8) = t.u;
    }
  } else {
    // ---------------- zero d_out (3 blocks) ----------------
    const int z = blk - (1602 + NFOR);
    float4 zz = make_float4(0.f, 0.f, 0.f, 0.f);
    for (int i = z * 256 + tid; i < NB * NCLS / 4; i += 3 * 256)
      ((float4*)out)[i] = zz;
  }
}

// ---------------------------------------------------------------------------
// forest_body: the full per-forest MFMA pipeline (R26 body, proven).
//  GEMM1(+ones denominator) -> LN1(softmax fold) -> Fn -> GEMM2 -> LN2 ->
//  H2 -> fc2 -> atomic. Reads/writes lsA rows [16wv,16wv+16)+{0,64} only
//  (wave-private within this body; gather writes are NOT wave-private).
// ---------------------------------------------------------------------------
__device__ __forceinline__ void forest_body(
    int f, int lane, int wv, int c, int q, int b0,
    unsigned short* lsA,
    const unsigned short* __restrict__ Bf,
    const unsigned short* __restrict__ W1f,
    const unsigned short* __restrict__ W2f,
    const float* __restrict__ ln1w, const float* __restrict__ ln1b,
    const float* __restrict__ fc1b,
    const float* __restrict__ ln2w, const float* __restrict__ ln2b,
    const float* __restrict__ fc2b,
    float* __restrict__ out, const short8* bp)
{
  const unsigned short* bbase = Bf + (size_t)f * 20480 + lane * 8;
  const unsigned short* pa0 = lsA + (wv * 16 + c) * 168 + q * 8;
  const unsigned short* pa1 = pa0 + 64 * 168;
  const short onev = (c == 0) ? (short)0x3F80 : (short)0;  // bf16 1.0, col 0
  short8 bones;
#pragma unroll
  for (int j = 0; j < 8; j++) bones[j] = onev;

  floatx4 acc0[8], acc1[8];
  floatx4 accs0 = (floatx4){0.f, 0.f, 0.f, 0.f};
  floatx4 accs1 = (floatx4){0.f, 0.f, 0.f, 0.f};
  __builtin_amdgcn_s_setprio(1);
  {
    short8 a0 = *(const short8*)(pa0);
    short8 a1 = *(const short8*)(pa1);
#pragma unroll
    for (int n = 0; n < 8; n++) {
      acc0[n] = __builtin_amdgcn_mfma_f32_16x16x32_bf16(a0, bp[n], (floatx4){0.f,0.f,0.f,0.f}, 0, 0, 0);
      acc1[n] = __builtin_amdgcn_mfma_f32_16x16x32_bf16(a1, bp[n], (floatx4){0.f,0.f,0.f,0.f}, 0, 0, 0);
    }
    accs0 = __builtin_amdgcn_mfma_f32_16x16x32_bf16(a0, bones, accs0, 0, 0, 0);
    accs1 = __builtin_amdgcn_mfma_f32_16x16x32_bf16(a1, bones, accs1, 0, 0, 0);
  }
#pragma unroll
  for (int kc = 1; kc < 5; kc++) {
    short8 a0 = *(const short8*)(pa0 + kc * 32);
    short8 a1 = *(const short8*)(pa1 + kc * 32);
#pragma unroll
    for (int n = 0; n < 8; n++) {
      short8 b = *(const short8*)(bbase + n * 2560 + kc * 512);
      acc0[n] = __builtin_amdgcn_mfma_f32_16x16x32_bf16(a0, b, acc0[n], 0, 0, 0);
      acc1[n] = __builtin_amdgcn_mfma_f32_16x16x32_bf16(a1, b, acc1[n], 0, 0, 0);
    }
    accs0 = __builtin_amdgcn_mfma_f32_16x16x32_bf16(a0, bones, accs0, 0, 0, 0);
    accs1 = __builtin_amdgcn_mfma_f32_16x16x32_bf16(a1, bones, accs1, 0, 0, 0);
  }
  __builtin_amdgcn_s_setprio(0);

  // ---- LN1 (both tiles): LN(x/s) == (x-mu)*rsqrt(var + eps*s^2) ----
  {
    float lw[8], lb[8];
#pragma unroll
    for (int n = 0; n < 8; n++) { lw[n] = ln1w[n * 16 + c]; lb[n] = ln1b[n * 16 + c]; }
#pragma unroll
    for (int rr = 0; rr < 4; rr++) {
      {
        float st = bcast16(accs0[rr]);
        float s1 = 0.f, s2 = 0.f;
#pragma unroll
        for (int n = 0; n < 8; n++) { float v = acc0[n][rr]; s1 += v; s2 += v * v; }
        s1 = rowsum16(s1);
        s2 = rowsum16(s2);
        float mu = s1 * (1.f / 128.f);
        float var = fmaxf(s2 * (1.f / 128.f) - mu * mu, 0.f);
        float rs = rsqrtf(var + GEPS * st * st);
#pragma unroll
        for (int n = 0; n < 8; n++)
          acc0[n][rr] = (acc0[n][rr] - mu) * rs * lw[n] + lb[n];
      }
      {
        float st = bcast16(accs1[rr]);
        float s1 = 0.f, s2 = 0.f;
#pragma unroll
        for (int n = 0; n < 8; n++) { float v = acc1[n][rr]; s1 += v; s2 += v * v; }
        s1 = rowsum16(s1);
        s2 = rowsum16(s2);
        float mu = s1 * (1.f / 128.f);
        float var = fmaxf(s2 * (1.f / 128.f) - mu * mu, 0.f);
        float rs = rsqrtf(var + GEPS * st * st);
#pragma unroll
        for (int n = 0; n < 8; n++)
          acc1[n][rr] = (acc1[n][rr] - mu) * rs * lw[n] + lb[n];
      }
    }
  }

  // ---- Fn -> lsA (A-layout bf16, wave-private rows; no barrier needed) ----
#pragma unroll
  for (int rr = 0; rr < 4; rr++)
#pragma unroll
    for (int n = 0; n < 8; n++) {
      lsA[(wv * 16 + q * 4 + rr) * 168 + n * 16 + c] =
          (unsigned short)f2bfu(acc0[n][rr]);
      lsA[(64 + wv * 16 + q * 4 + rr) * 168 + n * 16 + c] =
          (unsigned short)f2bfu(acc1[n][rr]);
    }

  // ---- GEMM2: H = Fn[128x128] @ fc1w[128x128] ----
  {
    short8 a00 = *(const short8*)(pa0);
    short8 a01 = *(const short8*)(pa0 + 32);
    short8 a02 = *(const short8*)(pa0 + 64);
    short8 a03 = *(const short8*)(pa0 + 96);
    short8 a10 = *(const short8*)(pa1);
    short8 a11 = *(const short8*)(pa1 + 32);
    short8 a12 = *(const short8*)(pa1 + 64);
    short8 a13 = *(const short8*)(pa1 + 96);
    const unsigned short* w1p = W1f + lane * 8;
    __builtin_amdgcn_s_setprio(1);
#pragma unroll
    for (int n = 0; n < 8; n++) {
      const unsigned short* wp = w1p + n * 2048;
      short8 b0v = *(const short8*)(wp);
      short8 b1v = *(const short8*)(wp + 512);
      short8 b2v = *(const short8*)(wp + 1024);
      short8 b3v = *(const short8*)(wp + 1536);
      floatx4 t0 = __builtin_amdgcn_mfma_f32_16x16x32_bf16(a00, b0v, (floatx4){0.f,0.f,0.f,0.f}, 0, 0, 0);
      t0 = __builtin_amdgcn_mfma_f32_16x16x32_bf16(a01, b1v, t0, 0, 0, 0);
      t0 = __builtin_amdgcn_mfma_f32_16x16x32_bf16(a02, b2v, t0, 0, 0, 0);
      t0 = __builtin_amdgcn_mfma_f32_16x16x32_bf16(a03, b3v, t0, 0, 0, 0);
      floatx4 t1 = __builtin_amdgcn_mfma_f32_16x16x32_bf16(a10, b0v, (floatx4){0.f,0.f,0.f,0.f}, 0, 0, 0);
      t1 = __builtin_amdgcn_mfma_f32_16x16x32_bf16(a11, b1v, t1, 0, 0, 0);
      t1 = __builtin_amdgcn_mfma_f32_16x16x32_bf16(a12, b2v, t1, 0, 0, 0);
      t1 = __builtin_amdgcn_mfma_f32_16x16x32_bf16(a13, b3v, t1, 0, 0, 0);
      acc0[n] = t0;
      acc1[n] = t1;
    }
    __builtin_amdgcn_s_setprio(0);
  }

  // ---- bias + ReLU + LN2 (both tiles, DPP row-reduce) ----
  {
    float fb[8], lw[8], lb[8];
#pragma unroll
    for (int n = 0; n < 8; n++) {
      fb[n] = fc1b[n * 16 + c];
      lw[n] = ln2w[n * 16 + c]; lb[n] = ln2b[n * 16 + c];
    }
#pragma unroll
    for (int rr = 0; rr < 4; rr++) {
      {
#pragma unroll
        for (int n = 0; n < 8; n++) acc0[n][rr] = fmaxf(acc0[n][rr] + fb[n], 0.f);
        float s1 = 0.f, s2 = 0.f;
#pragma unroll
        for (int n = 0; n < 8; n++) { float v = acc0[n][rr]; s1 += v; s2 += v * v; }
        s1 = rowsum16(s1);
        s2 = rowsum16(s2);
        float mu = s1 * (1.f / 128.f);
        float var = fmaxf(s2 * (1.f / 128.f) - mu * mu, 0.f);
        float rs = rsqrtf(var + GEPS);
#pragma unroll
        for (int n = 0; n < 8; n++)
          acc0[n][rr] = (acc0[n][rr] - mu) * rs * lw[n] + lb[n];
      }
      {
#pragma unroll
        for (int n = 0; n < 8; n++) acc1[n][rr] = fmaxf(acc1[n][rr] + fb[n], 0.f);
        float s1 = 0.f, s2 = 0.f;
#pragma unroll
        for (int n = 0; n < 8; n++) { float v = acc1[n][rr]; s1 += v; s2 += v * v; }
        s1 = rowsum16(s1);
        s2 = rowsum16(s2);
        float mu = s1 * (1.f / 128.f);
        float var = fmaxf(s2 * (1.f / 128.f) - mu * mu, 0.f);
        float rs = rsqrtf(var + GEPS);
#pragma unroll
        for (int n = 0; n < 8; n++)
          acc1[n][rr] = (acc1[n][rr] - mu) * rs * lw[n] + lb[n];
      }
    }
  }

  // ---- H2 -> lsA (A-layout, wave-private rows; no barrier) ----
#pragma unroll
  for (int rr = 0; rr < 4; rr++)
#pragma unroll
    for (int n = 0; n < 8; n++) {
      lsA[(wv * 16 + q * 4 + rr) * 168 + n * 16 + c] =
          (unsigned short)f2bfu(acc0[n][rr]);
      lsA[(64 + wv * 16 + q * 4 + rr) * 168 + n * 16 + c] =
          (unsigned short)f2bfu(acc1[n][rr]);
    }

  // ---- fc2 (16-col padded tile) + mean-atomic ----
  floatx4 o40 = (floatx4){0.f, 0.f, 0.f, 0.f};
  floatx4 o41 = (floatx4){0.f, 0.f, 0.f, 0.f};
#pragma unroll
  for (int kc = 0; kc < 4; kc++) {
    short8 a0 = *(const short8*)(pa0 + kc * 32);
    short8 a1 = *(const short8*)(pa1 + kc * 32);
    short8 b = *(const short8*)(W2f + kc * 512 + lane * 8);
    o40 = __builtin_amdgcn_mfma_f32_16x16x32_bf16(a0, b, o40, 0, 0, 0);
    o41 = __builtin_amdgcn_mfma_f32_16x16x32_bf16(a1, b, o41, 0, 0, 0);
  }
  if (c < NCLS) {
    float bias = fc2b[c];
#pragma unroll
    for (int rr = 0; rr < 4; rr++) {
      atomicAdd(out + (size_t)(b0 + wv * 16 + q * 4 + rr) * NCLS + c,
                (o40[rr] + bias) * 0.01f);
      atomicAdd(out + (size_t)(b0 + 64 + wv * 16 + q * 4 + rr) * NCLS + c,
                (o41[rr] + bias) * 0.01f);
    }
  }
}

// ---------------------------------------------------------------------------
// K3 (R27): TWO-FOREST software-pipelined block (grid 32 x 50).
//  Diagnosis: k3 is serial-chain latency-bound (42% idle, no pipe >43%);
//  every issue-rate lever is exhausted. This round hides the next forest's
//  gather (idx s_load + 40 scattered dword loads, the longest exposed chain)
//  under the current forest's ~5-6k-cycle compute pipeline:
//    gather f0 -> lsA; ISSUE f1 gather -> 40 regs (sched_barrier-pinned);
//    barrier; forest_body(f0); barrier; pack d1 -> lsA; barrier;
//    forest_body(f1).
//  R18 spill-proofing: straight-line (no loop), launch_bounds(256,3) (VGPR
//  budget ~500 at the LDS-capped 3 waves/SIMD -- d1[40] is free), statically
//  indexed arrays only. Spill tripwire: FETCH/WRITE must stay 23.3/25.6 MB.
// ---------------------------------------------------------------------------
__global__ __launch_bounds__(256, 3) void k3_mfma(
    const unsigned short* __restrict__ wT,    // [1600][B] bf16 exp(logits)^T
    const int* __restrict__ swr,
    const unsigned short* __restrict__ Bf,    // [f][8][5][64][8]
    const unsigned short* __restrict__ W1f,   // [8][4][64][8]
    const unsigned short* __restrict__ W2f,   // [4][64][8]
    const float* __restrict__ ln1w, const float* __restrict__ ln1b,
    const float* __restrict__ fc1b,
    const float* __restrict__ ln2w, const float* __restrict__ ln2b,
    const float* __restrict__ fc2b,
    float* __restrict__ out)
{
  __shared__ unsigned short lsA[128 * 168];   // 43008 B (rows 0-63 t0, 64-127 t1)

  const int tid = threadIdx.x;
  // ---- XCD-chunked swizzle: id -> (bx, forest-pair) ----
  const int id  = blockIdx.y * 32 + blockIdx.x;   // [0,1600)
  const int xcd = id & 7;
  const int pos = id >> 3;                        // [0,200)
  const int f0  = (pos >> 2) * 2;                 // even forest of the pair
  const int b0  = (xcd * 4 + (pos & 3)) * 128;
  const int lane = tid & 63;
  const int wv = __builtin_amdgcn_readfirstlane(tid >> 6);  // wave-uniform SGPR
  const int c = lane & 15, q = lane >> 4;

  const unsigned* wb32 = (const unsigned*)wT + (b0 >> 1) + lane;
  unsigned short* rp0 = lsA + (2 * lane) * 168 + wv * 40;   // row 2*lane
  unsigned short* rp1 = rp0 + 168;                          // row 2*lane+1

#define PKLO(a, b) (((a) & 0xFFFFu) | ((b) << 16))
#define PKHI(a, b) (((a) >> 16) | ((b) & 0xFFFF0000u))

  // ---- gather f0 (dword-pair, R26) -> lsA ----
  {
    const int* swf = swr + f0 * NEST + wv * 40;   // wave-uniform -> s_load
    int idx[40];
#pragma unroll
    for (int e = 0; e < 40; e++) idx[e] = swf[e];
    unsigned d[40];
#pragma unroll
    for (int e = 0; e < 40; e++)
      d[e] = wb32[(size_t)idx[e] * (NB / 2)];
#pragma unroll
    for (int k = 0; k < 5; k++) {
      uint4 lo = {PKLO(d[8*k+0], d[8*k+1]), PKLO(d[8*k+2], d[8*k+3]),
                  PKLO(d[8*k+4], d[8*k+5]), PKLO(d[8*k+6], d[8*k+7])};
      uint4 hi = {PKHI(d[8*k+0], d[8*k+1]), PKHI(d[8*k+2], d[8*k+3]),
                  PKHI(d[8*k+4], d[8*k+5]), PKHI(d[8*k+6], d[8*k+7])};
      *(uint4*)(rp0 + k * 8) = lo;
      *(uint4*)(rp1 + k * 8) = hi;
    }
  }

  // ---- ISSUE f1 gather now; results parked in regs through f0's body ----
  unsigned d1[40];
  {
    const int* swf1 = swr + (f0 + 1) * NEST + wv * 40;
    int idx1[40];
#pragma unroll
    for (int e = 0; e < 40; e++) idx1[e] = swf1[e];
#pragma unroll
    for (int e = 0; e < 40; e++)
      d1[e] = wb32[(size_t)idx1[e] * (NB / 2)];
  }
  __builtin_amdgcn_sched_barrier(0);   // pin: d1 loads issue before f0 body

  // ---- prefetch GEMM1 kc=0 B-fragments for f0 ----
  short8 bp0[8];
  {
    const unsigned short* bb = Bf + (size_t)f0 * 20480 + lane * 8;
#pragma unroll
    for (int n = 0; n < 8; n++) bp0[n] = *(const short8*)(bb + n * 2560);
  }

  __syncthreads();

  forest_body(f0, lane, wv, c, q, b0, lsA, Bf, W1f, W2f,
              ln1w, ln1b, fc1b, ln2w, ln2b, fc2b, out, bp0);

  // ---- prefetch f1 kc=0 B-fragments (overlaps other waves' f0 tail) ----
  short8 bp1[8];
  {
    const unsigned short* bb = Bf + (size_t)(f0 + 1) * 20480 + lane * 8;
#pragma unroll
    for (int n = 0; n < 8; n++) bp1[n] = *(const short8*)(bb + n * 2560);
  }

  __syncthreads();                     // all waves done reading lsA (f0)

  // ---- pack parked d1 -> lsA (loads completed long ago, under f0) ----
#pragma unroll
  for (int k = 0; k < 5; k++) {
    uint4 lo = {PKLO(d1[8*k+0], d1[8*k+1]), PKLO(d1[8*k+2], d1[8*k+3]),
                PKLO(d1[8*k+4], d1[8*k+5]), PKLO(d1[8*k+6], d1[8*k+7])};
    uint4 hi = {PKHI(d1[8*k+0], d1[8*k+1]), PKHI(d1[8*k+2], d1[8*k+3]),
                PKHI(d1[8*k+4], d1[8*k+5]), PKHI(d1[8*k+6], d1[8*k+7])};
    *(uint4*)(rp0 + k * 8) = lo;
    *(uint4*)(rp1 + k * 8) = hi;
  }
#undef PKLO
#undef PKHI

  __syncthreads();

  forest_body(f0 + 1, lane, wv, c, q, b0, lsA, Bf, W1f, W2f,
              ln1w, ln1b, fc1b, ln2w, ln2b, fc2b, out, bp1);
}

// ---------------------------------------------------------------------------
extern "C" void kernel_launch(void* const* d_in, const int* in_sizes, int n_in,
                              void* d_out, int out_size, void* d_ws, size_t ws_size,
                              hipStream_t stream)
{
  (void)in_sizes; (void)n_in; (void)ws_size; (void)out_size;
  const float* x    = (const float*)d_in[0];
  const float* w1   = (const float*)d_in[1];
  const float* b1   = (const float*)d_in[2];
  const int*   perm = (const int*)d_in[3];
  const float* gn1w = (const float*)d_in[4];
  const float* gn1b = (const float*)d_in[5];
  const float* c2w  = (const float*)d_in[6];
  const float* c2b  = (const float*)d_in[7];
  const float* gn2w = (const float*)d_in[8];
  const float* gn2b = (const float*)d_in[9];
  const float* c3w  = (const float*)d_in[10];
  const float* c3b  = (const float*)d_in[11];
  const int*   swr  = (const int*)d_in[12];
  const float* E    = (const float*)d_in[13];
  const float* ln1w = (const float*)d_in[14];
  const float* ln1b = (const float*)d_in[15];
  const float* fc1w = (const float*)d_in[16];
  const float* fc1b = (const float*)d_in[17];
  const float* ln2w = (const float*)d_in[18];
  const float* ln2b = (const float*)d_in[19];
  const float* fc2w = (const float*)d_in[20];
  const float* fc2b = (const float*)d_in[21];
  float* out = (float*)d_out;

  // workspace layout:
  //   [0, 13.1MB)       : wT exp-logits bf16 [1600][B]
  //   [13.1MB, +4.10MB) : Bf (100*20480 shorts)
  //   then W1f 32,768 B, W2f 4,096 B
  const size_t W_BYTES = (size_t)NB * NRODT * 2;     // 13,107,200
  unsigned short* wTbuf = (unsigned short*)d_ws;
  unsigned short* Bfb   = (unsigned short*)((char*)d_ws + W_BYTES);
  unsigned short* W1fb  = (unsigned short*)((char*)d_ws + W_BYTES + 4096000);
  unsigned short* W2fb  = (unsigned short*)((char*)d_ws + W_BYTES + 4096000 + 32768);

  k01_prep<<<1600 + NFOR + 2 + 3, 256, 0, stream>>>(
      x, w1, b1, perm, gn1w, gn1b, c2w, c2b, gn2w, gn2b, c3w, c3b,
      E, swr, fc1w, fc2w, wTbuf, Bfb, W1fb, W2fb, out);
  dim3 g3(NB / 128, NFOR / 2);
  k3_mfma<<<g3, 256, 0, stream>>>(wTbuf, swr, Bfb, W1fb, W2fb,
                                  ln1w, ln1b, fc1b, ln2w, ln2b, fc2b, out);
}

// Round 11
// 223.832 us; speedup vs baseline: 1.2508x; 1.2508x over previous
//
#include <hip/hip_runtime.h>
#include <hip/hip_bf16.h>
#include <stdint.h>

#define NB 4096
#define NCOL 100
#define NCOND 64
#define NTOTAL 6400
#define NRODT 1600
#define NEST 160
#define NFOR 100
#define NHID 128
#define NCLS 10
#define GEPS 1e-5f

typedef __attribute__((ext_vector_type(8))) short short8;
typedef __attribute__((ext_vector_type(4))) float floatx4;

// round-half-up f32->bf16: 2 VALU ops; tie-only difference vs RNE
__device__ __forceinline__ unsigned f2bfu(float x) {
  union { float f; unsigned u; } v; v.f = x;
  return (v.u + 0x8000u) >> 16;
}
__device__ __forceinline__ float bf2f(unsigned short u) {
  union { unsigned u; float f; } v; v.u = ((unsigned)u) << 16;
  return v.f;
}

// all-reduce sum over the 16-lane DPP row -- VALU pipe, no LDS.
__device__ __forceinline__ float rowsum16(float v) {
  union { float f; int i; } a, t;
  a.f = v;
  t.i = __builtin_amdgcn_update_dpp(0, a.i, 0x128, 0xf, 0xf, true); a.f += t.f; // ror:8
  t.i = __builtin_amdgcn_update_dpp(0, a.i, 0x124, 0xf, 0xf, true); a.f += t.f; // ror:4
  t.i = __builtin_amdgcn_update_dpp(0, a.i, 0x122, 0xf, 0xf, true); a.f += t.f; // ror:2
  t.i = __builtin_amdgcn_update_dpp(0, a.i, 0x121, 0xf, 0xf, true); a.f += t.f; // ror:1
  return a.f;
}

// broadcast the value of each 16-lane group's leader (lane & 0x30) to the
// whole group: ds_swizzle BitMode, and_mask=0x10 (keeps bit4 within 32-half).
__device__ __forceinline__ float bcast16(float v) {
  union { float f; int i; } a; a.f = v;
  a.i = __builtin_amdgcn_ds_swizzle(a.i, 0x0010);
  return a.f;
}

// ---------------------------------------------------------------------------
// K01: merged prep kernel (single launch). Unchanged (proven).
//  blocks [0,1600)    : k1 -- ConditionGeneration+perm+phi_2 -> exp(w)^T bf16
//  blocks [1600,1702) : k0 -- fragment-pack Bf / W1f / W2f (identity k-map)
//  blocks [1702,1705) : zero d_out
// ---------------------------------------------------------------------------
__global__ __launch_bounds__(256) void k01_prep(
    const float* __restrict__ x, const float* __restrict__ w1,
    const float* __restrict__ b1, const int* __restrict__ perm,
    const float* __restrict__ gn1w, const float* __restrict__ gn1b,
    const float* __restrict__ c2w, const float* __restrict__ c2b,
    const float* __restrict__ gn2w, const float* __restrict__ gn2b,
    const float* __restrict__ c3w, const float* __restrict__ c3b,
    const float* __restrict__ E, const int* __restrict__ swr,
    const float* __restrict__ fc1w, const float* __restrict__ fc2w,
    unsigned short* __restrict__ wT,
    unsigned short* __restrict__ Bf, unsigned short* __restrict__ W1f,
    unsigned short* __restrict__ W2f, float* __restrict__ out)
{
  __shared__ float xl[64 * NCOL];          // k1 path only (25.6 KB)
  __shared__ int ridx[NEST];               // k0 path only
  const int tid = threadIdx.x;
  const int blk = blockIdx.x;

  if (blk < 1600) {
    // ---------------- k1: phi_2 logits -> exp -> bf16, transposed ----------
    const int b0 = (blk & 63) * 64;
    const int g  = (blk >> 6) * 64 + (tid >> 2);
    const int i4 = tid & 3;
    for (int i = tid; i < 64 * NCOL; i += 256)
      xl[i] = x[(size_t)b0 * NCOL + i];
    __syncthreads();

    const int4 p4 = *(const int4*)(perm + 4 * g);
    const int pv[4] = {p4.x, p4.y, p4.z, p4.w};
    float w1v[4], b1v[4];
    int pc[4];
#pragma unroll
    for (int i = 0; i < 4; i++) {
      unsigned p = (unsigned)pv[i];
      unsigned j = p / 100u;
      unsigned cc = p - j * 100u;
      pc[i] = (int)cc;
      w1v[i] = w1[cc * NCOND + j];
      b1v[i] = b1[cc * NCOND + j];
    }
    const float4 g1w = *(const float4*)(gn1w + 4 * g);
    const float4 g1b = *(const float4*)(gn1b + 4 * g);
    const float4 cw0 = *(const float4*)(c2w + 16 * g);
    const float4 cw1 = *(const float4*)(c2w + 16 * g + 4);
    const float4 cw2 = *(const float4*)(c2w + 16 * g + 8);
    const float4 cw3 = *(const float4*)(c2w + 16 * g + 12);
    const float4 cbv = *(const float4*)(c2b + 4 * g);
    const float4 g2w = *(const float4*)(gn2w + 4 * g);
    const float4 g2b = *(const float4*)(gn2b + 4 * g);
    const float4 c3v = *(const float4*)(c3w + 4 * g);
    const float c3bv = c3b[g];

    for (int k = 0; k < 4; k++) {
      float v4[4];
#pragma unroll
      for (int j = 0; j < 4; j++) {
        const int bb = k * 16 + i4 * 4 + j;
        float O[4];
#pragma unroll
        for (int i = 0; i < 4; i++) {
          float a = xl[bb * NCOL + pc[i]] * w1v[i] + b1v[i];
          O[i] = 1.0f / (1.0f + __expf(-a));
        }
        float mu = 0.25f * (O[0] + O[1] + O[2] + O[3]);
        float d[4], var = 0.f;
#pragma unroll
        for (int i = 0; i < 4; i++) { d[i] = O[i] - mu; var += d[i] * d[i]; }
        float rs = rsqrtf(0.25f * var + GEPS);
        float xn0 = d[0] * rs * g1w.x + g1b.x;
        float xn1 = d[1] * rs * g1w.y + g1b.y;
        float xn2 = d[2] * rs * g1w.z + g1b.z;
        float xn3 = d[3] * rs * g1w.w + g1b.w;
        float h[4];
        h[0] = xn0*cw0.x + xn1*cw1.x + xn2*cw2.x + xn3*cw3.x + cbv.x;
        h[1] = xn0*cw0.y + xn1*cw1.y + xn2*cw2.y + xn3*cw3.y + cbv.y;
        h[2] = xn0*cw0.z + xn1*cw1.z + xn2*cw2.z + xn3*cw3.z + cbv.z;
        h[3] = xn0*cw0.w + xn1*cw1.w + xn2*cw2.w + xn3*cw3.w + cbv.w;
#pragma unroll
        for (int i = 0; i < 4; i++) h[i] = fmaxf(h[i], 0.f);
        float mu2 = 0.25f * (h[0] + h[1] + h[2] + h[3]);
        float e[4], var2 = 0.f;
#pragma unroll
        for (int i = 0; i < 4; i++) { e[i] = h[i] - mu2; var2 += e[i] * e[i]; }
        float rs2 = rsqrtf(0.25f * var2 + GEPS);
        float hn0 = e[0] * rs2 * g2w.x + g2b.x;
        float hn1 = e[1] * rs2 * g2w.y + g2b.y;
        float hn2 = e[2] * rs2 * g2w.z + g2b.z;
        float hn3 = e[3] * rs2 * g2w.w + g2b.w;
        v4[j] = hn0*c3v.x + hn1*c3v.y + hn2*c3v.z + hn3*c3v.w + c3bv;
      }
      // store exp(logit): k3's softmax numerator, once per unique (g,b)
      uint2 pk;
      pk.x = f2bfu(__expf(v4[0])) | (f2bfu(__expf(v4[1])) << 16);
      pk.y = f2bfu(__expf(v4[2])) | (f2bfu(__expf(v4[3])) << 16);
      *(uint2*)(wT + (size_t)g * NB + b0 + k * 16 + i4 * 4) = pk;
    }
  } else if (blk < 1600 + NFOR) {
    // ---------------- k0: Bf fragment pack ----------------
    const int fblk = blk - 1600;
    if (tid < NEST) ridx[tid] = swr[fblk * NEST + tid];
    __syncthreads();
    for (int m = tid; m < 2560; m += 256) {        // m = (n*5+kc)*64 + lane
      int lane = m & 63, rest = m >> 6;
      int kc = rest % 5, n = rest / 5;
      int q = lane >> 4, c = lane & 15;
      int e0 = kc * 32 + q * 8;
      int h = n * 16 + c;
      union { unsigned short v[8]; uint4 u; } t;
#pragma unroll
      for (int j = 0; j < 8; j++)
        t.v[j] = (unsigned short)f2bfu(E[(size_t)ridx[e0 + j] * NHID + h]);
      *(uint4*)(Bf + (size_t)fblk * 20480 + (size_t)m * 8) = t.u;
    }
  } else if (blk == 1600 + NFOR) {
    // ---------------- k0: W1f (identity k-map) ----------------
    for (int m = tid; m < 2048; m += 256) {        // m = (n*4+kc)*64 + lane
      int lane = m & 63, rest = m >> 6;
      int kc = rest & 3, n = rest >> 2;
      int q = lane >> 4, c = lane & 15;
      int k0 = kc * 32 + q * 8;
      int o = n * 16 + c;
      union { unsigned short v[8]; uint4 u; } t;
#pragma unroll
      for (int j = 0; j < 8; j++)
        t.v[j] = (unsigned short)f2bfu(fc1w[(size_t)(k0 + j) * NHID + o]);
      *(uint4*)(W1f + (size_t)m * 8) = t.u;
    }
  } else if (blk == 1601 + NFOR) {
    // ---------------- k0: W2f (identity k-map) ----------------
    for (int m = tid; m < 256; m += 256) {         // m = kc*64 + lane
      int lane = m & 63, kc = m >> 6;
      int q = lane >> 4, c = lane & 15;
      int k0 = kc * 32 + q * 8;
      union { unsigned short v[8]; uint4 u; } t;
#pragma unroll
      for (int j = 0; j < 8; j++)
        t.v[j] = (unsigned short)f2bfu(c < NCLS ? fc2w[(size_t)(k0 + j) * NCLS + c] : 0.f);
      *(uint4*)(W2f + (size_t)m * 8) = t.u;
    }
  } else {
    // ---------------- zero d_out (3 blocks) ----------------
    const int z = blk - (1602 + NFOR);
    float4 zz = make_float4(0.f, 0.f, 0.f, 0.f);
    for (int i = z * 256 + tid; i < NB * NCLS / 4; i += 3 * 256)
      ((float4*)out)[i] = zz;
  }
}

// ---------------------------------------------------------------------------
// K3 (R28): BARRIER-FREE direct-to-register A-fragment gather.
//  R27 post-mortem: parking 40 dwords across an inlined forest_body spilled
//  (FETCH/WRITE tripwire fired) -- revert that. New mechanism: within a wave,
//  the union over q of fragment indices e=kc*32+q*8+j covers all 160
//  estimators, so each wave loads EXACTLY its own MFMA A-fragments (80
//  ushort loads; t1 = t0+128B immediate) with NO LDS staging, NO pack, and
//  NO __syncthreads() anywhere (Fn/H2 LDS rows are wave-private). Kills the
//  gather->pack->barrier convoy: each wave starts GEMM1 when ITS loads land.
//  Indices per-lane via 10 int4 loads (L1-broadcast). lsA shrinks to
//  128x136 shorts (34,816 B): 4 blocks/CU iff VGPR<=128 (139 KB total --
//  unlike R24/R25's exactly-160KB, this has 24 KB slack).
//  launch_bounds(256,3): allocator never squeezed (R24 lesson); straight-
//  line, statically-indexed register arrays only (R18 lesson).
//  Spill tripwire: FETCH/WRITE must stay ~23.3/25.6 MB.
// ---------------------------------------------------------------------------
__global__ __launch_bounds__(256, 3) void k3_mfma(
    const unsigned short* __restrict__ wT,    // [1600][B] bf16 exp(logits)^T
    const int* __restrict__ swr,
    const unsigned short* __restrict__ Bf,    // [f][8][5][64][8]
    const unsigned short* __restrict__ W1f,   // [8][4][64][8]
    const unsigned short* __restrict__ W2f,   // [4][64][8]
    const float* __restrict__ ln1w, const float* __restrict__ ln1b,
    const float* __restrict__ fc1b,
    const float* __restrict__ ln2w, const float* __restrict__ ln2b,
    const float* __restrict__ fc2b,
    float* __restrict__ out)
{
  __shared__ unsigned short lsA[128 * 136];   // 34,816 B (Fn/H2 only)

  const int tid = threadIdx.x;
  // ---- XCD-chunked swizzle: id -> (bx, f) ----
  const int id  = blockIdx.y * 32 + blockIdx.x;   // linear dispatch id, [0,3200)
  const int xcd = id & 7;
  const int pos = id >> 3;                        // [0,400)
  const int f   = pos >> 2;                       // [0,100)
  const int b0  = (xcd * 4 + (pos & 3)) * 128;    // bx in [4*xcd, 4*xcd+4)
  const int lane = tid & 63;
  const int wv = __builtin_amdgcn_readfirstlane(tid >> 6);  // wave-uniform SGPR
  const int c = lane & 15, q = lane >> 4;

  // ---- direct-to-register A-fragment gather (both tiles), no LDS ----
  // lane (c,q) needs e = kc*32+q*8+j for kc in [0,5), j in [0,8);
  // value = exp(w)[swr[f][e]][b0 + wv*16 + c]  (t1: +64 columns = +128 B).
  short8 a0f[5], a1f[5];
  {
    const int* swq = swr + f * NEST + q * 8;      // per-lane (q) index base
    int4 iva[5], ivb[5];
#pragma unroll
    for (int kc = 0; kc < 5; kc++) {
      iva[kc] = *(const int4*)(swq + kc * 32);
      ivb[kc] = *(const int4*)(swq + kc * 32 + 4);
    }
    const unsigned short* wcol = wT + b0 + wv * 16 + c;
#pragma unroll
    for (int kc = 0; kc < 5; kc++) {
      int e[8] = {iva[kc].x, iva[kc].y, iva[kc].z, iva[kc].w,
                  ivb[kc].x, ivb[kc].y, ivb[kc].z, ivb[kc].w};
      unsigned short t0[8], t1[8];
#pragma unroll
      for (int j = 0; j < 8; j++) {
        const unsigned short* p = wcol + (size_t)e[j] * NB;
        t0[j] = p[0];                             // tile 0 column
        t1[j] = p[64];                            // tile 1 column (+128 B)
      }
#pragma unroll
      for (int j = 0; j < 8; j++) {
        a0f[kc][j] = (short)t0[j];
        a1f[kc][j] = (short)t1[j];
      }
    }
  }

  // ---- GEMM1: (exp-ws)[128x160] @ Ep[160x128], A from regs, B inline ----
  //      + ones-column MFMA computing the softmax denominators
  const unsigned short* bbase = Bf + (size_t)f * 20480 + lane * 8;
  const short onev = (c == 0) ? (short)0x3F80 : (short)0;  // bf16 1.0 in col 0
  short8 bones;
#pragma unroll
  for (int j = 0; j < 8; j++) bones[j] = onev;

  floatx4 acc0[8], acc1[8];
  floatx4 accs0 = (floatx4){0.f, 0.f, 0.f, 0.f};
  floatx4 accs1 = (floatx4){0.f, 0.f, 0.f, 0.f};
  __builtin_amdgcn_s_setprio(1);
#pragma unroll
  for (int n = 0; n < 8; n++) {
    short8 b = *(const short8*)(bbase + n * 2560);
    acc0[n] = __builtin_amdgcn_mfma_f32_16x16x32_bf16(a0f[0], b, (floatx4){0.f,0.f,0.f,0.f}, 0, 0, 0);
    acc1[n] = __builtin_amdgcn_mfma_f32_16x16x32_bf16(a1f[0], b, (floatx4){0.f,0.f,0.f,0.f}, 0, 0, 0);
  }
  accs0 = __builtin_amdgcn_mfma_f32_16x16x32_bf16(a0f[0], bones, accs0, 0, 0, 0);
  accs1 = __builtin_amdgcn_mfma_f32_16x16x32_bf16(a1f[0], bones, accs1, 0, 0, 0);
#pragma unroll
  for (int kc = 1; kc < 5; kc++) {
#pragma unroll
    for (int n = 0; n < 8; n++) {
      short8 b = *(const short8*)(bbase + n * 2560 + kc * 512);
      acc0[n] = __builtin_amdgcn_mfma_f32_16x16x32_bf16(a0f[kc], b, acc0[n], 0, 0, 0);
      acc1[n] = __builtin_amdgcn_mfma_f32_16x16x32_bf16(a1f[kc], b, acc1[n], 0, 0, 0);
    }
    accs0 = __builtin_amdgcn_mfma_f32_16x16x32_bf16(a0f[kc], bones, accs0, 0, 0, 0);
    accs1 = __builtin_amdgcn_mfma_f32_16x16x32_bf16(a1f[kc], bones, accs1, 0, 0, 0);
  }
  __builtin_amdgcn_s_setprio(0);

  // ---- LN1 (both tiles): LN(x/s) == (x-mu)*rsqrt(var + eps*s^2) ----
  {
    float lw[8], lb[8];
#pragma unroll
    for (int n = 0; n < 8; n++) { lw[n] = ln1w[n * 16 + c]; lb[n] = ln1b[n * 16 + c]; }
#pragma unroll
    for (int rr = 0; rr < 4; rr++) {
      {
        float st = bcast16(accs0[rr]);         // denominator, row q*4+rr (t0)
        float s1 = 0.f, s2 = 0.f;
#pragma unroll
        for (int n = 0; n < 8; n++) { float v = acc0[n][rr]; s1 += v; s2 += v * v; }
        s1 = rowsum16(s1);
        s2 = rowsum16(s2);
        float mu = s1 * (1.f / 128.f);
        float var = fmaxf(s2 * (1.f / 128.f) - mu * mu, 0.f);
        float rs = rsqrtf(var + GEPS * st * st);
#pragma unroll
        for (int n = 0; n < 8; n++)
          acc0[n][rr] = (acc0[n][rr] - mu) * rs * lw[n] + lb[n];
      }
      {
        float st = bcast16(accs1[rr]);         // denominator, row q*4+rr (t1)
        float s1 = 0.f, s2 = 0.f;
#pragma unroll
        for (int n = 0; n < 8; n++) { float v = acc1[n][rr]; s1 += v; s2 += v * v; }
        s1 = rowsum16(s1);
        s2 = rowsum16(s2);
        float mu = s1 * (1.f / 128.f);
        float var = fmaxf(s2 * (1.f / 128.f) - mu * mu, 0.f);
        float rs = rsqrtf(var + GEPS * st * st);
#pragma unroll
        for (int n = 0; n < 8; n++)
          acc1[n][rr] = (acc1[n][rr] - mu) * rs * lw[n] + lb[n];
      }
    }
  }

  // ---- Fn -> lsA (A-layout bf16, wave-private rows; barrier-free) ----
#pragma unroll
  for (int rr = 0; rr < 4; rr++)
#pragma unroll
    for (int n = 0; n < 8; n++) {
      lsA[(wv * 16 + q * 4 + rr) * 136 + n * 16 + c] =
          (unsigned short)f2bfu(acc0[n][rr]);
      lsA[(64 + wv * 16 + q * 4 + rr) * 136 + n * 16 + c] =
          (unsigned short)f2bfu(acc1[n][rr]);
    }

  const unsigned short* pa0 = lsA + (wv * 16 + c) * 136 + q * 8;
  const unsigned short* pa1 = pa0 + 64 * 136;

  // ---- GEMM2: H = Fn[128x128] @ fc1w[128x128]; W1f loaded once per 2 tiles -
  {
    short8 a00 = *(const short8*)(pa0);
    short8 a01 = *(const short8*)(pa0 + 32);
    short8 a02 = *(const short8*)(pa0 + 64);
    short8 a03 = *(const short8*)(pa0 + 96);
    short8 a10 = *(const short8*)(pa1);
    short8 a11 = *(const short8*)(pa1 + 32);
    short8 a12 = *(const short8*)(pa1 + 64);
    short8 a13 = *(const short8*)(pa1 + 96);
    const unsigned short* w1p = W1f + lane * 8;
    __builtin_amdgcn_s_setprio(1);
#pragma unroll
    for (int n = 0; n < 8; n++) {
      const unsigned short* wp = w1p + n * 2048;
      short8 b0v = *(const short8*)(wp);
      short8 b1v = *(const short8*)(wp + 512);
      short8 b2v = *(const short8*)(wp + 1024);
      short8 b3v = *(const short8*)(wp + 1536);
      floatx4 t0 = __builtin_amdgcn_mfma_f32_16x16x32_bf16(a00, b0v, (floatx4){0.f,0.f,0.f,0.f}, 0, 0, 0);
      t0 = __builtin_amdgcn_mfma_f32_16x16x32_bf16(a01, b1v, t0, 0, 0, 0);
      t0 = __builtin_amdgcn_mfma_f32_16x16x32_bf16(a02, b2v, t0, 0, 0, 0);
      t0 = __builtin_amdgcn_mfma_f32_16x16x32_bf16(a03, b3v, t0, 0, 0, 0);
      floatx4 t1 = __builtin_amdgcn_mfma_f32_16x16x32_bf16(a10, b0v, (floatx4){0.f,0.f,0.f,0.f}, 0, 0, 0);
      t1 = __builtin_amdgcn_mfma_f32_16x16x32_bf16(a11, b1v, t1, 0, 0, 0);
      t1 = __builtin_amdgcn_mfma_f32_16x16x32_bf16(a12, b2v, t1, 0, 0, 0);
      t1 = __builtin_amdgcn_mfma_f32_16x16x32_bf16(a13, b3v, t1, 0, 0, 0);
      acc0[n] = t0;
      acc1[n] = t1;
    }
    __builtin_amdgcn_s_setprio(0);
  }

  // ---- bias + ReLU + LN2 (both tiles, DPP row-reduce) ----
  {
    float fb[8], lw[8], lb[8];
#pragma unroll
    for (int n = 0; n < 8; n++) {
      fb[n] = fc1b[n * 16 + c];
      lw[n] = ln2w[n * 16 + c]; lb[n] = ln2b[n * 16 + c];
    }
#pragma unroll
    for (int rr = 0; rr < 4; rr++) {
      {
#pragma unroll
        for (int n = 0; n < 8; n++) acc0[n][rr] = fmaxf(acc0[n][rr] + fb[n], 0.f);
        float s1 = 0.f, s2 = 0.f;
#pragma unroll
        for (int n = 0; n < 8; n++) { float v = acc0[n][rr]; s1 += v; s2 += v * v; }
        s1 = rowsum16(s1);
        s2 = rowsum16(s2);
        float mu = s1 * (1.f / 128.f);
        float var = fmaxf(s2 * (1.f / 128.f) - mu * mu, 0.f);
        float rs = rsqrtf(var + GEPS);
#pragma unroll
        for (int n = 0; n < 8; n++)
          acc0[n][rr] = (acc0[n][rr] - mu) * rs * lw[n] + lb[n];
      }
      {
#pragma unroll
        for (int n = 0; n < 8; n++) acc1[n][rr] = fmaxf(acc1[n][rr] + fb[n], 0.f);
        float s1 = 0.f, s2 = 0.f;
#pragma unroll
        for (int n = 0; n < 8; n++) { float v = acc1[n][rr]; s1 += v; s2 += v * v; }
        s1 = rowsum16(s1);
        s2 = rowsum16(s2);
        float mu = s1 * (1.f / 128.f);
        float var = fmaxf(s2 * (1.f / 128.f) - mu * mu, 0.f);
        float rs = rsqrtf(var + GEPS);
#pragma unroll
        for (int n = 0; n < 8; n++)
          acc1[n][rr] = (acc1[n][rr] - mu) * rs * lw[n] + lb[n];
      }
    }
  }

  // ---- H2 -> lsA (A-layout, wave-private rows; barrier-free) ----
#pragma unroll
  for (int rr = 0; rr < 4; rr++)
#pragma unroll
    for (int n = 0; n < 8; n++) {
      lsA[(wv * 16 + q * 4 + rr) * 136 + n * 16 + c] =
          (unsigned short)f2bfu(acc0[n][rr]);
      lsA[(64 + wv * 16 + q * 4 + rr) * 136 + n * 16 + c] =
          (unsigned short)f2bfu(acc1[n][rr]);
    }

  // ---- fc2 (16-col padded tile), W2f loaded once per 2 tiles ----
  floatx4 o40 = (floatx4){0.f, 0.f, 0.f, 0.f};
  floatx4 o41 = (floatx4){0.f, 0.f, 0.f, 0.f};
#pragma unroll
  for (int kc = 0; kc < 4; kc++) {
    short8 a0 = *(const short8*)(pa0 + kc * 32);
    short8 a1 = *(const short8*)(pa1 + kc * 32);
    short8 b = *(const short8*)(W2f + kc * 512 + lane * 8);
    o40 = __builtin_amdgcn_mfma_f32_16x16x32_bf16(a0, b, o40, 0, 0, 0);
    o41 = __builtin_amdgcn_mfma_f32_16x16x32_bf16(a1, b, o41, 0, 0, 0);
  }
  if (c < NCLS) {
    float bias = fc2b[c];
#pragma unroll
    for (int rr = 0; rr < 4; rr++) {
      atomicAdd(out + (size_t)(b0 + wv * 16 + q * 4 + rr) * NCLS + c,
                (o40[rr] + bias) * 0.01f);
      atomicAdd(out + (size_t)(b0 + 64 + wv * 16 + q * 4 + rr) * NCLS + c,
                (o41[rr] + bias) * 0.01f);
    }
  }
}

// ---------------------------------------------------------------------------
extern "C" void kernel_launch(void* const* d_in, const int* in_sizes, int n_in,
                              void* d_out, int out_size, void* d_ws, size_t ws_size,
                              hipStream_t stream)
{
  (void)in_sizes; (void)n_in; (void)ws_size; (void)out_size;
  const float* x    = (const float*)d_in[0];
  const float* w1   = (const float*)d_in[1];
  const float* b1   = (const float*)d_in[2];
  const int*   perm = (const int*)d_in[3];
  const float* gn1w = (const float*)d_in[4];
  const float* gn1b = (const float*)d_in[5];
  const float* c2w  = (const float*)d_in[6];
  const float* c2b  = (const float*)d_in[7];
  const float* gn2w = (const float*)d_in[8];
  const float* gn2b = (const float*)d_in[9];
  const float* c3w  = (const float*)d_in[10];
  const float* c3b  = (const float*)d_in[11];
  const int*   swr  = (const int*)d_in[12];
  const float* E    = (const float*)d_in[13];
  const float* ln1w = (const float*)d_in[14];
  const float* ln1b = (const float*)d_in[15];
  const float* fc1w = (const float*)d_in[16];
  const float* fc1b = (const float*)d_in[17];
  const float* ln2w = (const float*)d_in[18];
  const float* ln2b = (const float*)d_in[19];
  const float* fc2w = (const float*)d_in[20];
  const float* fc2b = (const float*)d_in[21];
  float* out = (float*)d_out;

  // workspace layout:
  //   [0, 13.1MB)       : wT exp-logits bf16 [1600][B]
  //   [13.1MB, +4.10MB) : Bf (100*20480 shorts)
  //   then W1f 32,768 B, W2f 4,096 B
  const size_t W_BYTES = (size_t)NB * NRODT * 2;     // 13,107,200
  unsigned short* wTbuf = (unsigned short*)d_ws;
  unsigned short* Bfb   = (unsigned short*)((char*)d_ws + W_BYTES);
  unsigned short* W1fb  = (unsigned short*)((char*)d_ws + W_BYTES + 4096000);
  unsigned short* W2fb  = (unsigned short*)((char*)d_ws + W_BYTES + 4096000 + 32768);

  k01_prep<<<1600 + NFOR + 2 + 3, 256, 0, stream>>>(
      x, w1, b1, perm, gn1w, gn1b, c2w, c2b, gn2w, gn2b, c3w, c3b,
      E, swr, fc1w, fc2w, wTbuf, Bfb, W1fb, W2fb, out);
  dim3 g3(NB / 128, NFOR);
  k3_mfma<<<g3, 256, 0, stream>>>(wTbuf, swr, Bfb, W1fb, W2fb,
                                  ln1w, ln1b, fc1b, ln2w, ln2b, fc2b, out);
}

// Round 12
// 208.271 us; speedup vs baseline: 1.3442x; 1.0747x over previous
//
#include <hip/hip_runtime.h>
#include <hip/hip_bf16.h>
#include <stdint.h>

#define NB 4096
#define NCOL 100
#define NCOND 64
#define NTOTAL 6400
#define NRODT 1600
#define NEST 160
#define NFOR 100
#define NHID 128
#define NCLS 10
#define GEPS 1e-5f

typedef __attribute__((ext_vector_type(8))) short short8;
typedef __attribute__((ext_vector_type(4))) float floatx4;

// round-half-up f32->bf16: 2 VALU ops; tie-only difference vs RNE
__device__ __forceinline__ unsigned f2bfu(float x) {
  union { float f; unsigned u; } v; v.f = x;
  return (v.u + 0x8000u) >> 16;
}
__device__ __forceinline__ float bf2f(unsigned short u) {
  union { unsigned u; float f; } v; v.u = ((unsigned)u) << 16;
  return v.f;
}

// all-reduce sum over the 16-lane DPP row -- VALU pipe, no LDS.
__device__ __forceinline__ float rowsum16(float v) {
  union { float f; int i; } a, t;
  a.f = v;
  t.i = __builtin_amdgcn_update_dpp(0, a.i, 0x128, 0xf, 0xf, true); a.f += t.f; // ror:8
  t.i = __builtin_amdgcn_update_dpp(0, a.i, 0x124, 0xf, 0xf, true); a.f += t.f; // ror:4
  t.i = __builtin_amdgcn_update_dpp(0, a.i, 0x122, 0xf, 0xf, true); a.f += t.f; // ror:2
  t.i = __builtin_amdgcn_update_dpp(0, a.i, 0x121, 0xf, 0xf, true); a.f += t.f; // ror:1
  return a.f;
}

// broadcast the value of each 16-lane group's leader (lane & 0x30) to the
// whole group: ds_swizzle BitMode, and_mask=0x10 (keeps bit4 within 32-half).
__device__ __forceinline__ float bcast16(float v) {
  union { float f; int i; } a; a.f = v;
  a.i = __builtin_amdgcn_ds_swizzle(a.i, 0x0010);
  return a.f;
}

// ---------------------------------------------------------------------------
// K01: merged prep kernel (single launch). Unchanged (proven).
//  blocks [0,1600)    : k1 -- ConditionGeneration+perm+phi_2 -> exp(w)^T bf16
//  blocks [1600,1702) : k0 -- fragment-pack Bf / W1f / W2f (identity k-map)
//  blocks [1702,1705) : zero d_out
// ---------------------------------------------------------------------------
__global__ __launch_bounds__(256) void k01_prep(
    const float* __restrict__ x, const float* __restrict__ w1,
    const float* __restrict__ b1, const int* __restrict__ perm,
    const float* __restrict__ gn1w, const float* __restrict__ gn1b,
    const float* __restrict__ c2w, const float* __restrict__ c2b,
    const float* __restrict__ gn2w, const float* __restrict__ gn2b,
    const float* __restrict__ c3w, const float* __restrict__ c3b,
    const float* __restrict__ E, const int* __restrict__ swr,
    const float* __restrict__ fc1w, const float* __restrict__ fc2w,
    unsigned short* __restrict__ wT,
    unsigned short* __restrict__ Bf, unsigned short* __restrict__ W1f,
    unsigned short* __restrict__ W2f, float* __restrict__ out)
{
  __shared__ float xl[64 * NCOL];          // k1 path only (25.6 KB)
  __shared__ int ridx[NEST];               // k0 path only
  const int tid = threadIdx.x;
  const int blk = blockIdx.x;

  if (blk < 1600) {
    // ---------------- k1: phi_2 logits -> exp -> bf16, transposed ----------
    const int b0 = (blk & 63) * 64;
    const int g  = (blk >> 6) * 64 + (tid >> 2);
    const int i4 = tid & 3;
    for (int i = tid; i < 64 * NCOL; i += 256)
      xl[i] = x[(size_t)b0 * NCOL + i];
    __syncthreads();

    const int4 p4 = *(const int4*)(perm + 4 * g);
    const int pv[4] = {p4.x, p4.y, p4.z, p4.w};
    float w1v[4], b1v[4];
    int pc[4];
#pragma unroll
    for (int i = 0; i < 4; i++) {
      unsigned p = (unsigned)pv[i];
      unsigned j = p / 100u;
      unsigned cc = p - j * 100u;
      pc[i] = (int)cc;
      w1v[i] = w1[cc * NCOND + j];
      b1v[i] = b1[cc * NCOND + j];
    }
    const float4 g1w = *(const float4*)(gn1w + 4 * g);
    const float4 g1b = *(const float4*)(gn1b + 4 * g);
    const float4 cw0 = *(const float4*)(c2w + 16 * g);
    const float4 cw1 = *(const float4*)(c2w + 16 * g + 4);
    const float4 cw2 = *(const float4*)(c2w + 16 * g + 8);
    const float4 cw3 = *(const float4*)(c2w + 16 * g + 12);
    const float4 cbv = *(const float4*)(c2b + 4 * g);
    const float4 g2w = *(const float4*)(gn2w + 4 * g);
    const float4 g2b = *(const float4*)(gn2b + 4 * g);
    const float4 c3v = *(const float4*)(c3w + 4 * g);
    const float c3bv = c3b[g];

    for (int k = 0; k < 4; k++) {
      float v4[4];
#pragma unroll
      for (int j = 0; j < 4; j++) {
        const int bb = k * 16 + i4 * 4 + j;
        float O[4];
#pragma unroll
        for (int i = 0; i < 4; i++) {
          float a = xl[bb * NCOL + pc[i]] * w1v[i] + b1v[i];
          O[i] = 1.0f / (1.0f + __expf(-a));
        }
        float mu = 0.25f * (O[0] + O[1] + O[2] + O[3]);
        float d[4], var = 0.f;
#pragma unroll
        for (int i = 0; i < 4; i++) { d[i] = O[i] - mu; var += d[i] * d[i]; }
        float rs = rsqrtf(0.25f * var + GEPS);
        float xn0 = d[0] * rs * g1w.x + g1b.x;
        float xn1 = d[1] * rs * g1w.y + g1b.y;
        float xn2 = d[2] * rs * g1w.z + g1b.z;
        float xn3 = d[3] * rs * g1w.w + g1b.w;
        float h[4];
        h[0] = xn0*cw0.x + xn1*cw1.x + xn2*cw2.x + xn3*cw3.x + cbv.x;
        h[1] = xn0*cw0.y + xn1*cw1.y + xn2*cw2.y + xn3*cw3.y + cbv.y;
        h[2] = xn0*cw0.z + xn1*cw1.z + xn2*cw2.z + xn3*cw3.z + cbv.z;
        h[3] = xn0*cw0.w + xn1*cw1.w + xn2*cw2.w + xn3*cw3.w + cbv.w;
#pragma unroll
        for (int i = 0; i < 4; i++) h[i] = fmaxf(h[i], 0.f);
        float mu2 = 0.25f * (h[0] + h[1] + h[2] + h[3]);
        float e[4], var2 = 0.f;
#pragma unroll
        for (int i = 0; i < 4; i++) { e[i] = h[i] - mu2; var2 += e[i] * e[i]; }
        float rs2 = rsqrtf(0.25f * var2 + GEPS);
        float hn0 = e[0] * rs2 * g2w.x + g2b.x;
        float hn1 = e[1] * rs2 * g2w.y + g2b.y;
        float hn2 = e[2] * rs2 * g2w.z + g2b.z;
        float hn3 = e[3] * rs2 * g2w.w + g2b.w;
        v4[j] = hn0*c3v.x + hn1*c3v.y + hn2*c3v.z + hn3*c3v.w + c3bv;
      }
      // store exp(logit): k3's softmax numerator, once per unique (g,b)
      uint2 pk;
      pk.x = f2bfu(__expf(v4[0])) | (f2bfu(__expf(v4[1])) << 16);
      pk.y = f2bfu(__expf(v4[2])) | (f2bfu(__expf(v4[3])) << 16);
      *(uint2*)(wT + (size_t)g * NB + b0 + k * 16 + i4 * 4) = pk;
    }
  } else if (blk < 1600 + NFOR) {
    // ---------------- k0: Bf fragment pack ----------------
    const int fblk = blk - 1600;
    if (tid < NEST) ridx[tid] = swr[fblk * NEST + tid];
    __syncthreads();
    for (int m = tid; m < 2560; m += 256) {        // m = (n*5+kc)*64 + lane
      int lane = m & 63, rest = m >> 6;
      int kc = rest % 5, n = rest / 5;
      int q = lane >> 4, c = lane & 15;
      int e0 = kc * 32 + q * 8;
      int h = n * 16 + c;
      union { unsigned short v[8]; uint4 u; } t;
#pragma unroll
      for (int j = 0; j < 8; j++)
        t.v[j] = (unsigned short)f2bfu(E[(size_t)ridx[e0 + j] * NHID + h]);
      *(uint4*)(Bf + (size_t)fblk * 20480 + (size_t)m * 8) = t.u;
    }
  } else if (blk == 1600 + NFOR) {
    // ---------------- k0: W1f (identity k-map) ----------------
    for (int m = tid; m < 2048; m += 256) {        // m = (n*4+kc)*64 + lane
      int lane = m & 63, rest = m >> 6;
      int kc = rest & 3, n = rest >> 2;
      int q = lane >> 4, c = lane & 15;
      int k0 = kc * 32 + q * 8;
      int o = n * 16 + c;
      union { unsigned short v[8]; uint4 u; } t;
#pragma unroll
      for (int j = 0; j < 8; j++)
        t.v[j] = (unsigned short)f2bfu(fc1w[(size_t)(k0 + j) * NHID + o]);
      *(uint4*)(W1f + (size_t)m * 8) = t.u;
    }
  } else if (blk == 1601 + NFOR) {
    // ---------------- k0: W2f (identity k-map) ----------------
    for (int m = tid; m < 256; m += 256) {         // m = kc*64 + lane
      int lane = m & 63, kc = m >> 6;
      int q = lane >> 4, c = lane & 15;
      int k0 = kc * 32 + q * 8;
      union { unsigned short v[8]; uint4 u; } t;
#pragma unroll
      for (int j = 0; j < 8; j++)
        t.v[j] = (unsigned short)f2bfu(c < NCLS ? fc2w[(size_t)(k0 + j) * NCLS + c] : 0.f);
      *(uint4*)(W2f + (size_t)m * 8) = t.u;
    }
  } else {
    // ---------------- zero d_out (3 blocks) ----------------
    const int z = blk - (1602 + NFOR);
    float4 zz = make_float4(0.f, 0.f, 0.f, 0.f);
    for (int i = z * 256 + tid; i < NB * NCLS / 4; i += 3 * 256)
      ((float4*)out)[i] = zz;
  }
}

// ---------------------------------------------------------------------------
// K3 (R29): R26 REVERT (proven best: 205.5 total, k3 84.6) + register
//  double-buffered B-operands in GEMM1/GEMM2. R28 post-mortem: the gather's
//  coalescing is load-bearing -- keep the dword-pair LDS gather. New delta:
//  issue step k+1's B-fragment loads BEFORE step k's MFMAs (explicitly named
//  bA*/bB* buffers: no dynamic indexing, no loop-carry, peak ~120 VGPR under
//  the (256,3) cap of 170). Hides the ~200-300cy L2 latency of each B step
//  under the current step's MFMAs + wave rotation.
//  Spill tripwire: FETCH/WRITE must stay ~23.3/25.6 MB.
// ---------------------------------------------------------------------------
__global__ __launch_bounds__(256, 3) void k3_mfma(
    const unsigned short* __restrict__ wT,    // [1600][B] bf16 exp(logits)^T
    const int* __restrict__ swr,
    const unsigned short* __restrict__ Bf,    // [f][8][5][64][8]
    const unsigned short* __restrict__ W1f,   // [8][4][64][8]
    const unsigned short* __restrict__ W2f,   // [4][64][8]
    const float* __restrict__ ln1w, const float* __restrict__ ln1b,
    const float* __restrict__ fc1b,
    const float* __restrict__ ln2w, const float* __restrict__ ln2b,
    const float* __restrict__ fc2b,
    float* __restrict__ out)
{
  __shared__ unsigned short lsA[128 * 168];   // 43008 B (rows 0-63 t0, 64-127 t1)

  const int tid = threadIdx.x;
  // ---- XCD-chunked swizzle: id -> (bx, f) ----
  const int id  = blockIdx.y * 32 + blockIdx.x;   // linear dispatch id, [0,3200)
  const int xcd = id & 7;
  const int pos = id >> 3;                        // [0,400)
  const int f   = pos >> 2;                       // [0,100)
  const int b0  = (xcd * 4 + (pos & 3)) * 128;    // bx in [4*xcd, 4*xcd+4)
  const int lane = tid & 63;
  const int wv = __builtin_amdgcn_readfirstlane(tid >> 6);  // wave-uniform SGPR
  const int c = lane & 15, q = lane >> 4;

  // ---- gather: wave wv covers e in [40wv,40wv+40); dword-pair loads ----
  // lane l reads wT[e][b0+2l .. b0+2l+1] as one dword (rows 2l, 2l+1).
  {
    const int* swf = swr + f * NEST + wv * 40;    // wave-uniform -> s_load
    int idx[40];
#pragma unroll
    for (int e = 0; e < 40; e++) idx[e] = swf[e];

    const unsigned* wb32 = (const unsigned*)wT + (b0 >> 1) + lane;
    unsigned d[40];
#pragma unroll
    for (int e = 0; e < 40; e++)
      d[e] = wb32[(size_t)idx[e] * (NB / 2)];     // 40 loads in flight

    unsigned short* rp0 = lsA + (2 * lane) * 168 + wv * 40;   // row 2l
    unsigned short* rp1 = rp0 + 168;                          // row 2l+1

#define PKLO(a, b) (((a) & 0xFFFFu) | ((b) << 16))
#define PKHI(a, b) (((a) >> 16) | ((b) & 0xFFFF0000u))
#pragma unroll
    for (int k = 0; k < 5; k++) {
      uint4 lo = {PKLO(d[8*k+0], d[8*k+1]), PKLO(d[8*k+2], d[8*k+3]),
                  PKLO(d[8*k+4], d[8*k+5]), PKLO(d[8*k+6], d[8*k+7])};
      uint4 hi = {PKHI(d[8*k+0], d[8*k+1]), PKHI(d[8*k+2], d[8*k+3]),
                  PKHI(d[8*k+4], d[8*k+5]), PKHI(d[8*k+6], d[8*k+7])};
      *(uint4*)(rp0 + k * 8) = lo;
      *(uint4*)(rp1 + k * 8) = hi;
    }
#undef PKLO
#undef PKHI
  }

  const unsigned short* bbase = Bf + (size_t)f * 20480 + lane * 8;

  // ---- double-buffered B fragments: explicitly named (rule #20 safe) ----
  short8 bA0, bA1, bA2, bA3, bA4, bA5, bA6, bA7;
  short8 bB0, bB1, bB2, bB3, bB4, bB5, bB6, bB7;

#define G1_LOAD(P, kcc) \
  P##0 = *(const short8*)(bbase + 0*2560 + (kcc)*512); \
  P##1 = *(const short8*)(bbase + 1*2560 + (kcc)*512); \
  P##2 = *(const short8*)(bbase + 2*2560 + (kcc)*512); \
  P##3 = *(const short8*)(bbase + 3*2560 + (kcc)*512); \
  P##4 = *(const short8*)(bbase + 4*2560 + (kcc)*512); \
  P##5 = *(const short8*)(bbase + 5*2560 + (kcc)*512); \
  P##6 = *(const short8*)(bbase + 6*2560 + (kcc)*512); \
  P##7 = *(const short8*)(bbase + 7*2560 + (kcc)*512);

  // prefetch kc=0 before the barrier (independent of gather)
  G1_LOAD(bA, 0)

  __syncthreads();                     // the ONLY barrier

  // ---- GEMM1: (exp-ws)[128x160] @ Ep[160x128], B double-buffered ----
  //      + ones-column MFMA computing the softmax denominators
  const unsigned short* pa0 = lsA + (wv * 16 + c) * 168 + q * 8;
  const unsigned short* pa1 = pa0 + 64 * 168;
  const short onev = (c == 0) ? (short)0x3F80 : (short)0;  // bf16 1.0 in col 0
  short8 bones;
#pragma unroll
  for (int j = 0; j < 8; j++) bones[j] = onev;

  floatx4 acc0[8], acc1[8];
#pragma unroll
  for (int n = 0; n < 8; n++) {
    acc0[n] = (floatx4){0.f, 0.f, 0.f, 0.f};
    acc1[n] = (floatx4){0.f, 0.f, 0.f, 0.f};
  }
  floatx4 accs0 = (floatx4){0.f, 0.f, 0.f, 0.f};
  floatx4 accs1 = (floatx4){0.f, 0.f, 0.f, 0.f};

#define G1_MFMA(P, kcc) \
  { short8 a0 = *(const short8*)(pa0 + (kcc)*32); \
    short8 a1 = *(const short8*)(pa1 + (kcc)*32); \
    acc0[0] = __builtin_amdgcn_mfma_f32_16x16x32_bf16(a0, P##0, acc0[0],0,0,0); \
    acc1[0] = __builtin_amdgcn_mfma_f32_16x16x32_bf16(a1, P##0, acc1[0],0,0,0); \
    acc0[1] = __builtin_amdgcn_mfma_f32_16x16x32_bf16(a0, P##1, acc0[1],0,0,0); \
    acc1[1] = __builtin_amdgcn_mfma_f32_16x16x32_bf16(a1, P##1, acc1[1],0,0,0); \
    acc0[2] = __builtin_amdgcn_mfma_f32_16x16x32_bf16(a0, P##2, acc0[2],0,0,0); \
    acc1[2] = __builtin_amdgcn_mfma_f32_16x16x32_bf16(a1, P##2, acc1[2],0,0,0); \
    acc0[3] = __builtin_amdgcn_mfma_f32_16x16x32_bf16(a0, P##3, acc0[3],0,0,0); \
    acc1[3] = __builtin_amdgcn_mfma_f32_16x16x32_bf16(a1, P##3, acc1[3],0,0,0); \
    acc0[4] = __builtin_amdgcn_mfma_f32_16x16x32_bf16(a0, P##4, acc0[4],0,0,0); \
    acc1[4] = __builtin_amdgcn_mfma_f32_16x16x32_bf16(a1, P##4, acc1[4],0,0,0); \
    acc0[5] = __builtin_amdgcn_mfma_f32_16x16x32_bf16(a0, P##5, acc0[5],0,0,0); \
    acc1[5] = __builtin_amdgcn_mfma_f32_16x16x32_bf16(a1, P##5, acc1[5],0,0,0); \
    acc0[6] = __builtin_amdgcn_mfma_f32_16x16x32_bf16(a0, P##6, acc0[6],0,0,0); \
    acc1[6] = __builtin_amdgcn_mfma_f32_16x16x32_bf16(a1, P##6, acc1[6],0,0,0); \
    acc0[7] = __builtin_amdgcn_mfma_f32_16x16x32_bf16(a0, P##7, acc0[7],0,0,0); \
    acc1[7] = __builtin_amdgcn_mfma_f32_16x16x32_bf16(a1, P##7, acc1[7],0,0,0); \
    accs0   = __builtin_amdgcn_mfma_f32_16x16x32_bf16(a0, bones, accs0,0,0,0); \
    accs1   = __builtin_amdgcn_mfma_f32_16x16x32_bf16(a1, bones, accs1,0,0,0); }

  __builtin_amdgcn_s_setprio(1);
  G1_LOAD(bB, 1)   // prefetch kc1 under kc0's MFMAs
  G1_MFMA(bA, 0)
  G1_LOAD(bA, 2)
  G1_MFMA(bB, 1)
  G1_LOAD(bB, 3)
  G1_MFMA(bA, 2)
  G1_LOAD(bA, 4)
  G1_MFMA(bB, 3)
  G1_MFMA(bA, 4)
  __builtin_amdgcn_s_setprio(0);
#undef G1_MFMA
#undef G1_LOAD

  // ---- LN1 (both tiles): LN(x/s) == (x-mu)*rsqrt(var + eps*s^2) ----
  {
    float lw[8], lb[8];
#pragma unroll
    for (int n = 0; n < 8; n++) { lw[n] = ln1w[n * 16 + c]; lb[n] = ln1b[n * 16 + c]; }
#pragma unroll
    for (int rr = 0; rr < 4; rr++) {
      {
        float st = bcast16(accs0[rr]);         // denominator, row q*4+rr (t0)
        float s1 = 0.f, s2 = 0.f;
#pragma unroll
        for (int n = 0; n < 8; n++) { float v = acc0[n][rr]; s1 += v; s2 += v * v; }
        s1 = rowsum16(s1);
        s2 = rowsum16(s2);
        float mu = s1 * (1.f / 128.f);
        float var = fmaxf(s2 * (1.f / 128.f) - mu * mu, 0.f);
        float rs = rsqrtf(var + GEPS * st * st);
#pragma unroll
        for (int n = 0; n < 8; n++)
          acc0[n][rr] = (acc0[n][rr] - mu) * rs * lw[n] + lb[n];
      }
      {
        float st = bcast16(accs1[rr]);         // denominator, row q*4+rr (t1)
        float s1 = 0.f, s2 = 0.f;
#pragma unroll
        for (int n = 0; n < 8; n++) { float v = acc1[n][rr]; s1 += v; s2 += v * v; }
        s1 = rowsum16(s1);
        s2 = rowsum16(s2);
        float mu = s1 * (1.f / 128.f);
        float var = fmaxf(s2 * (1.f / 128.f) - mu * mu, 0.f);
        float rs = rsqrtf(var + GEPS * st * st);
#pragma unroll
        for (int n = 0; n < 8; n++)
          acc1[n][rr] = (acc1[n][rr] - mu) * rs * lw[n] + lb[n];
      }
    }
  }

  // ---- Fn -> lsA (A-layout bf16, wave-private rows; no barrier needed) ----
#pragma unroll
  for (int rr = 0; rr < 4; rr++)
#pragma unroll
    for (int n = 0; n < 8; n++) {
      lsA[(wv * 16 + q * 4 + rr) * 168 + n * 16 + c] =
          (unsigned short)f2bfu(acc0[n][rr]);
      lsA[(64 + wv * 16 + q * 4 + rr) * 168 + n * 16 + c] =
          (unsigned short)f2bfu(acc1[n][rr]);
    }

  // ---- GEMM2: H = Fn[128x128] @ fc1w[128x128], W1f double-buffered ----
  {
    short8 a00 = *(const short8*)(pa0);
    short8 a01 = *(const short8*)(pa0 + 32);
    short8 a02 = *(const short8*)(pa0 + 64);
    short8 a03 = *(const short8*)(pa0 + 96);
    short8 a10 = *(const short8*)(pa1);
    short8 a11 = *(const short8*)(pa1 + 32);
    short8 a12 = *(const short8*)(pa1 + 64);
    short8 a13 = *(const short8*)(pa1 + 96);
    const unsigned short* w1p = W1f + lane * 8;

#define G2_LOAD(P, nn) \
    P##0 = *(const short8*)(w1p + (nn)*2048); \
    P##1 = *(const short8*)(w1p + (nn)*2048 + 512); \
    P##2 = *(const short8*)(w1p + (nn)*2048 + 1024); \
    P##3 = *(const short8*)(w1p + (nn)*2048 + 1536);

#define G2_MFMA(P, nn) \
    { floatx4 t0 = __builtin_amdgcn_mfma_f32_16x16x32_bf16(a00, P##0, (floatx4){0.f,0.f,0.f,0.f},0,0,0); \
      t0 = __builtin_amdgcn_mfma_f32_16x16x32_bf16(a01, P##1, t0,0,0,0); \
      t0 = __builtin_amdgcn_mfma_f32_16x16x32_bf16(a02, P##2, t0,0,0,0); \
      t0 = __builtin_amdgcn_mfma_f32_16x16x32_bf16(a03, P##3, t0,0,0,0); \
      floatx4 t1 = __builtin_amdgcn_mfma_f32_16x16x32_bf16(a10, P##0, (floatx4){0.f,0.f,0.f,0.f},0,0,0); \
      t1 = __builtin_amdgcn_mfma_f32_16x16x32_bf16(a11, P##1, t1,0,0,0); \
      t1 = __builtin_amdgcn_mfma_f32_16x16x32_bf16(a12, P##2, t1,0,0,0); \
      t1 = __builtin_amdgcn_mfma_f32_16x16x32_bf16(a13, P##3, t1,0,0,0); \
      acc0[nn] = t0; \
      acc1[nn] = t1; }

    __builtin_amdgcn_s_setprio(1);
    G2_LOAD(bA, 0)
    G2_LOAD(bB, 1)
    G2_MFMA(bA, 0)
    G2_LOAD(bA, 2)
    G2_MFMA(bB, 1)
    G2_LOAD(bB, 3)
    G2_MFMA(bA, 2)
    G2_LOAD(bA, 4)
    G2_MFMA(bB, 3)
    G2_LOAD(bB, 5)
    G2_MFMA(bA, 4)
    G2_LOAD(bA, 6)
    G2_MFMA(bB, 5)
    G2_LOAD(bB, 7)
    G2_MFMA(bA, 6)
    G2_MFMA(bB, 7)
    __builtin_amdgcn_s_setprio(0);
#undef G2_MFMA
#undef G2_LOAD
  }

  // ---- bias + ReLU + LN2 (both tiles, DPP row-reduce) ----
  {
    float fb[8], lw[8], lb[8];
#pragma unroll
    for (int n = 0; n < 8; n++) {
      fb[n] = fc1b[n * 16 + c];
      lw[n] = ln2w[n * 16 + c]; lb[n] = ln2b[n * 16 + c];
    }
#pragma unroll
    for (int rr = 0; rr < 4; rr++) {
      {
#pragma unroll
        for (int n = 0; n < 8; n++) acc0[n][rr] = fmaxf(acc0[n][rr] + fb[n], 0.f);
        float s1 = 0.f, s2 = 0.f;
#pragma unroll
        for (int n = 0; n < 8; n++) { float v = acc0[n][rr]; s1 += v; s2 += v * v; }
        s1 = rowsum16(s1);
        s2 = rowsum16(s2);
        float mu = s1 * (1.f / 128.f);
        float var = fmaxf(s2 * (1.f / 128.f) - mu * mu, 0.f);
        float rs = rsqrtf(var + GEPS);
#pragma unroll
        for (int n = 0; n < 8; n++)
          acc0[n][rr] = (acc0[n][rr] - mu) * rs * lw[n] + lb[n];
      }
      {
#pragma unroll
        for (int n = 0; n < 8; n++) acc1[n][rr] = fmaxf(acc1[n][rr] + fb[n], 0.f);
        float s1 = 0.f, s2 = 0.f;
#pragma unroll
        for (int n = 0; n < 8; n++) { float v = acc1[n][rr]; s1 += v; s2 += v * v; }
        s1 = rowsum16(s1);
        s2 = rowsum16(s2);
        float mu = s1 * (1.f / 128.f);
        float var = fmaxf(s2 * (1.f / 128.f) - mu * mu, 0.f);
        float rs = rsqrtf(var + GEPS);
#pragma unroll
        for (int n = 0; n < 8; n++)
          acc1[n][rr] = (acc1[n][rr] - mu) * rs * lw[n] + lb[n];
      }
    }
  }

  // ---- H2 -> lsA (A-layout, wave-private rows; no barrier) ----
#pragma unroll
  for (int rr = 0; rr < 4; rr++)
#pragma unroll
    for (int n = 0; n < 8; n++) {
      lsA[(wv * 16 + q * 4 + rr) * 168 + n * 16 + c] =
          (unsigned short)f2bfu(acc0[n][rr]);
      lsA[(64 + wv * 16 + q * 4 + rr) * 168 + n * 16 + c] =
          (unsigned short)f2bfu(acc1[n][rr]);
    }

  // ---- fc2 (16-col padded tile), W2f loaded once per 2 tiles ----
  floatx4 o40 = (floatx4){0.f, 0.f, 0.f, 0.f};
  floatx4 o41 = (floatx4){0.f, 0.f, 0.f, 0.f};
#pragma unroll
  for (int kc = 0; kc < 4; kc++) {
    short8 a0 = *(const short8*)(pa0 + kc * 32);
    short8 a1 = *(const short8*)(pa1 + kc * 32);
    short8 b = *(const short8*)(W2f + kc * 512 + lane * 8);
    o40 = __builtin_amdgcn_mfma_f32_16x16x32_bf16(a0, b, o40, 0, 0, 0);
    o41 = __builtin_amdgcn_mfma_f32_16x16x32_bf16(a1, b, o41, 0, 0, 0);
  }
  if (c < NCLS) {
    float bias = fc2b[c];
#pragma unroll
    for (int rr = 0; rr < 4; rr++) {
      atomicAdd(out + (size_t)(b0 + wv * 16 + q * 4 + rr) * NCLS + c,
                (o40[rr] + bias) * 0.01f);
      atomicAdd(out + (size_t)(b0 + 64 + wv * 16 + q * 4 + rr) * NCLS + c,
                (o41[rr] + bias) * 0.01f);
    }
  }
}

// ---------------------------------------------------------------------------
extern "C" void kernel_launch(void* const* d_in, const int* in_sizes, int n_in,
                              void* d_out, int out_size, void* d_ws, size_t ws_size,
                              hipStream_t stream)
{
  (void)in_sizes; (void)n_in; (void)ws_size; (void)out_size;
  const float* x    = (const float*)d_in[0];
  const float* w1   = (const float*)d_in[1];
  const float* b1   = (const float*)d_in[2];
  const int*   perm = (const int*)d_in[3];
  const float* gn1w = (const float*)d_in[4];
  const float* gn1b = (const float*)d_in[5];
  const float* c2w  = (const float*)d_in[6];
  const float* c2b  = (const float*)d_in[7];
  const float* gn2w = (const float*)d_in[8];
  const float* gn2b = (const float*)d_in[9];
  const float* c3w  = (const float*)d_in[10];
  const float* c3b  = (const float*)d_in[11];
  const int*   swr  = (const int*)d_in[12];
  const float* E    = (const float*)d_in[13];
  const float* ln1w = (const float*)d_in[14];
  const float* ln1b = (const float*)d_in[15];
  const float* fc1w = (const float*)d_in[16];
  const float* fc1b = (const float*)d_in[17];
  const float* ln2w = (const float*)d_in[18];
  const float* ln2b = (const float*)d_in[19];
  const float* fc2w = (const float*)d_in[20];
  const float* fc2b = (const float*)d_in[21];
  float* out = (float*)d_out;

  // workspace layout:
  //   [0, 13.1MB)       : wT exp-logits bf16 [1600][B]
  //   [13.1MB, +4.10MB) : Bf (100*20480 shorts)
  //   then W1f 32,768 B, W2f 4,096 B
  const size_t W_BYTES = (size_t)NB * NRODT * 2;     // 13,107,200
  unsigned short* wTbuf = (unsigned short*)d_ws;
  unsigned short* Bfb   = (unsigned short*)((char*)d_ws + W_BYTES);
  unsigned short* W1fb  = (unsigned short*)((char*)d_ws + W_BYTES + 4096000);
  unsigned short* W2fb  = (unsigned short*)((char*)d_ws + W_BYTES + 4096000 + 32768);

  k01_prep<<<1600 + NFOR + 2 + 3, 256, 0, stream>>>(
      x, w1, b1, perm, gn1w, gn1b, c2w, c2b, gn2w, gn2b, c3w, c3b,
      E, swr, fc1w, fc2w, wTbuf, Bfb, W1fb, W2fb, out);
  dim3 g3(NB / 128, NFOR);
  k3_mfma<<<g3, 256, 0, stream>>>(wTbuf, swr, Bfb, W1fb, W2fb,
                                  ln1w, ln1b, fc1b, ln2w, ln2b, fc2b, out);
}

// Round 13
// 205.214 us; speedup vs baseline: 1.3643x; 1.0149x over previous
//
#include <hip/hip_runtime.h>
#include <hip/hip_bf16.h>
#include <stdint.h>

#define NB 4096
#define NCOL 100
#define NCOND 64
#define NTOTAL 6400
#define NRODT 1600
#define NEST 160
#define NFOR 100
#define NHID 128
#define NCLS 10
#define GEPS 1e-5f

typedef __attribute__((ext_vector_type(8))) short short8;
typedef __attribute__((ext_vector_type(4))) float floatx4;

// round-half-up f32->bf16: 2 VALU ops; tie-only difference vs RNE
__device__ __forceinline__ unsigned f2bfu(float x) {
  union { float f; unsigned u; } v; v.f = x;
  return (v.u + 0x8000u) >> 16;
}
__device__ __forceinline__ float bf2f(unsigned short u) {
  union { unsigned u; float f; } v; v.u = ((unsigned)u) << 16;
  return v.f;
}

// all-reduce sum over the 16-lane DPP row -- VALU pipe, no LDS.
__device__ __forceinline__ float rowsum16(float v) {
  union { float f; int i; } a, t;
  a.f = v;
  t.i = __builtin_amdgcn_update_dpp(0, a.i, 0x128, 0xf, 0xf, true); a.f += t.f; // ror:8
  t.i = __builtin_amdgcn_update_dpp(0, a.i, 0x124, 0xf, 0xf, true); a.f += t.f; // ror:4
  t.i = __builtin_amdgcn_update_dpp(0, a.i, 0x122, 0xf, 0xf, true); a.f += t.f; // ror:2
  t.i = __builtin_amdgcn_update_dpp(0, a.i, 0x121, 0xf, 0xf, true); a.f += t.f; // ror:1
  return a.f;
}

// broadcast the value of each 16-lane group's leader (lane & 0x30) to the
// whole group: ds_swizzle BitMode, and_mask=0x10 (keeps bit4 within 32-half).
__device__ __forceinline__ float bcast16(float v) {
  union { float f; int i; } a; a.f = v;
  a.i = __builtin_amdgcn_ds_swizzle(a.i, 0x0010);
  return a.f;
}

// ---------------------------------------------------------------------------
// K01 (R30): k1 split to b=32 chunks for TLP.
//  k1 diagnosis (blind -- k01 never enters top-5, so <83.5us): serial
//  per-thread chain (LDS reads -> sigmoid -> GN -> conv -> GN -> conv -> exp)
//  x16 iterations; arithmetic cost ~10us => latency-bound, like k3 was.
//  b=32: LDS 25.6->12.8 KB => 6->8 blocks/CU (32-wave HW cap), k-loop 4->2
//  (compiler fully unrolls trip-2 => 8 parallel chains of ILP), finer tail.
//  blocks [0,3200)    : k1 -- ConditionGeneration+perm+phi_2 -> exp(w)^T bf16
//  blocks [3200,3300) : k0 -- Bf fragment pack
//  block  3300 / 3301 : W1f / W2f pack
//  blocks [3302,3305) : zero d_out
// ---------------------------------------------------------------------------
__global__ __launch_bounds__(256) void k01_prep(
    const float* __restrict__ x, const float* __restrict__ w1,
    const float* __restrict__ b1, const int* __restrict__ perm,
    const float* __restrict__ gn1w, const float* __restrict__ gn1b,
    const float* __restrict__ c2w, const float* __restrict__ c2b,
    const float* __restrict__ gn2w, const float* __restrict__ gn2b,
    const float* __restrict__ c3w, const float* __restrict__ c3b,
    const float* __restrict__ E, const int* __restrict__ swr,
    const float* __restrict__ fc1w, const float* __restrict__ fc2w,
    unsigned short* __restrict__ wT,
    unsigned short* __restrict__ Bf, unsigned short* __restrict__ W1f,
    unsigned short* __restrict__ W2f, float* __restrict__ out)
{
  __shared__ float xl[32 * NCOL];          // k1 path only (12.8 KB)
  __shared__ int ridx[NEST];               // k0 path only
  const int tid = threadIdx.x;
  const int blk = blockIdx.x;

  if (blk < 3200) {
    // ---------------- k1: phi_2 logits -> exp -> bf16, transposed ----------
    const int b0 = (blk & 127) * 32;
    const int g  = (blk >> 7) * 64 + (tid >> 2);
    const int i4 = tid & 3;
    for (int i = tid; i < 32 * NCOL; i += 256)
      xl[i] = x[(size_t)b0 * NCOL + i];
    __syncthreads();

    const int4 p4 = *(const int4*)(perm + 4 * g);
    const int pv[4] = {p4.x, p4.y, p4.z, p4.w};
    float w1v[4], b1v[4];
    int pc[4];
#pragma unroll
    for (int i = 0; i < 4; i++) {
      unsigned p = (unsigned)pv[i];
      unsigned j = p / 100u;
      unsigned cc = p - j * 100u;
      pc[i] = (int)cc;
      w1v[i] = w1[cc * NCOND + j];
      b1v[i] = b1[cc * NCOND + j];
    }
    const float4 g1w = *(const float4*)(gn1w + 4 * g);
    const float4 g1b = *(const float4*)(gn1b + 4 * g);
    const float4 cw0 = *(const float4*)(c2w + 16 * g);
    const float4 cw1 = *(const float4*)(c2w + 16 * g + 4);
    const float4 cw2 = *(const float4*)(c2w + 16 * g + 8);
    const float4 cw3 = *(const float4*)(c2w + 16 * g + 12);
    const float4 cbv = *(const float4*)(c2b + 4 * g);
    const float4 g2w = *(const float4*)(gn2w + 4 * g);
    const float4 g2b = *(const float4*)(gn2b + 4 * g);
    const float4 c3v = *(const float4*)(c3w + 4 * g);
    const float c3bv = c3b[g];

#pragma unroll
    for (int k = 0; k < 2; k++) {
      float v4[4];
#pragma unroll
      for (int j = 0; j < 4; j++) {
        const int bb = k * 16 + i4 * 4 + j;
        float O[4];
#pragma unroll
        for (int i = 0; i < 4; i++) {
          float a = xl[bb * NCOL + pc[i]] * w1v[i] + b1v[i];
          O[i] = 1.0f / (1.0f + __expf(-a));
        }
        float mu = 0.25f * (O[0] + O[1] + O[2] + O[3]);
        float d[4], var = 0.f;
#pragma unroll
        for (int i = 0; i < 4; i++) { d[i] = O[i] - mu; var += d[i] * d[i]; }
        float rs = rsqrtf(0.25f * var + GEPS);
        float xn0 = d[0] * rs * g1w.x + g1b.x;
        float xn1 = d[1] * rs * g1w.y + g1b.y;
        float xn2 = d[2] * rs * g1w.z + g1b.z;
        float xn3 = d[3] * rs * g1w.w + g1b.w;
        float h[4];
        h[0] = xn0*cw0.x + xn1*cw1.x + xn2*cw2.x + xn3*cw3.x + cbv.x;
        h[1] = xn0*cw0.y + xn1*cw1.y + xn2*cw2.y + xn3*cw3.y + cbv.y;
        h[2] = xn0*cw0.z + xn1*cw1.z + xn2*cw2.z + xn3*cw3.z + cbv.z;
        h[3] = xn0*cw0.w + xn1*cw1.w + xn2*cw2.w + xn3*cw3.w + cbv.w;
#pragma unroll
        for (int i = 0; i < 4; i++) h[i] = fmaxf(h[i], 0.f);
        float mu2 = 0.25f * (h[0] + h[1] + h[2] + h[3]);
        float e[4], var2 = 0.f;
#pragma unroll
        for (int i = 0; i < 4; i++) { e[i] = h[i] - mu2; var2 += e[i] * e[i]; }
        float rs2 = rsqrtf(0.25f * var2 + GEPS);
        float hn0 = e[0] * rs2 * g2w.x + g2b.x;
        float hn1 = e[1] * rs2 * g2w.y + g2b.y;
        float hn2 = e[2] * rs2 * g2w.z + g2b.z;
        float hn3 = e[3] * rs2 * g2w.w + g2b.w;
        v4[j] = hn0*c3v.x + hn1*c3v.y + hn2*c3v.z + hn3*c3v.w + c3bv;
      }
      // store exp(logit): k3's softmax numerator, once per unique (g,b)
      uint2 pk;
      pk.x = f2bfu(__expf(v4[0])) | (f2bfu(__expf(v4[1])) << 16);
      pk.y = f2bfu(__expf(v4[2])) | (f2bfu(__expf(v4[3])) << 16);
      *(uint2*)(wT + (size_t)g * NB + b0 + k * 16 + i4 * 4) = pk;
    }
  } else if (blk < 3200 + NFOR) {
    // ---------------- k0: Bf fragment pack ----------------
    const int fblk = blk - 3200;
    if (tid < NEST) ridx[tid] = swr[fblk * NEST + tid];
    __syncthreads();
    for (int m = tid; m < 2560; m += 256) {        // m = (n*5+kc)*64 + lane
      int lane = m & 63, rest = m >> 6;
      int kc = rest % 5, n = rest / 5;
      int q = lane >> 4, c = lane & 15;
      int e0 = kc * 32 + q * 8;
      int h = n * 16 + c;
      union { unsigned short v[8]; uint4 u; } t;
#pragma unroll
      for (int j = 0; j < 8; j++)
        t.v[j] = (unsigned short)f2bfu(E[(size_t)ridx[e0 + j] * NHID + h]);
      *(uint4*)(Bf + (size_t)fblk * 20480 + (size_t)m * 8) = t.u;
    }
  } else if (blk == 3200 + NFOR) {
    // ---------------- k0: W1f (identity k-map) ----------------
    for (int m = tid; m < 2048; m += 256) {        // m = (n*4+kc)*64 + lane
      int lane = m & 63, rest = m >> 6;
      int kc = rest & 3, n = rest >> 2;
      int q = lane >> 4, c = lane & 15;
      int k0 = kc * 32 + q * 8;
      int o = n * 16 + c;
      union { unsigned short v[8]; uint4 u; } t;
#pragma unroll
      for (int j = 0; j < 8; j++)
        t.v[j] = (unsigned short)f2bfu(fc1w[(size_t)(k0 + j) * NHID + o]);
      *(uint4*)(W1f + (size_t)m * 8) = t.u;
    }
  } else if (blk == 3201 + NFOR) {
    // ---------------- k0: W2f (identity k-map) ----------------
    for (int m = tid; m < 256; m += 256) {         // m = kc*64 + lane
      int lane = m & 63, kc = m >> 6;
      int q = lane >> 4, c = lane & 15;
      int k0 = kc * 32 + q * 8;
      union { unsigned short v[8]; uint4 u; } t;
#pragma unroll
      for (int j = 0; j < 8; j++)
        t.v[j] = (unsigned short)f2bfu(c < NCLS ? fc2w[(size_t)(k0 + j) * NCLS + c] : 0.f);
      *(uint4*)(W2f + (size_t)m * 8) = t.u;
    }
  } else {
    // ---------------- zero d_out (3 blocks) ----------------
    const int z = blk - (3202 + NFOR);
    float4 zz = make_float4(0.f, 0.f, 0.f, 0.f);
    for (int i = z * 256 + tid; i < NB * NCLS / 4; i += 3 * 256)
      ((float4*)out)[i] = zz;
  }
}

// ---------------------------------------------------------------------------
// K3 (R30 = R29, FROZEN): structural floor confirmed (R29 flat). Dword-pair
//  gather, 336-stride LDS, ones-column denominator, XCD swizzle, setprio,
//  register double-buffered B-operands, one barrier, launch_bounds(256,3).
// ---------------------------------------------------------------------------
__global__ __launch_bounds__(256, 3) void k3_mfma(
    const unsigned short* __restrict__ wT,    // [1600][B] bf16 exp(logits)^T
    const int* __restrict__ swr,
    const unsigned short* __restrict__ Bf,    // [f][8][5][64][8]
    const unsigned short* __restrict__ W1f,   // [8][4][64][8]
    const unsigned short* __restrict__ W2f,   // [4][64][8]
    const float* __restrict__ ln1w, const float* __restrict__ ln1b,
    const float* __restrict__ fc1b,
    const float* __restrict__ ln2w, const float* __restrict__ ln2b,
    const float* __restrict__ fc2b,
    float* __restrict__ out)
{
  __shared__ unsigned short lsA[128 * 168];   // 43008 B (rows 0-63 t0, 64-127 t1)

  const int tid = threadIdx.x;
  // ---- XCD-chunked swizzle: id -> (bx, f) ----
  const int id  = blockIdx.y * 32 + blockIdx.x;   // linear dispatch id, [0,3200)
  const int xcd = id & 7;
  const int pos = id >> 3;                        // [0,400)
  const int f   = pos >> 2;                       // [0,100)
  const int b0  = (xcd * 4 + (pos & 3)) * 128;    // bx in [4*xcd, 4*xcd+4)
  const int lane = tid & 63;
  const int wv = __builtin_amdgcn_readfirstlane(tid >> 6);  // wave-uniform SGPR
  const int c = lane & 15, q = lane >> 4;

  // ---- gather: wave wv covers e in [40wv,40wv+40); dword-pair loads ----
  {
    const int* swf = swr + f * NEST + wv * 40;    // wave-uniform -> s_load
    int idx[40];
#pragma unroll
    for (int e = 0; e < 40; e++) idx[e] = swf[e];

    const unsigned* wb32 = (const unsigned*)wT + (b0 >> 1) + lane;
    unsigned d[40];
#pragma unroll
    for (int e = 0; e < 40; e++)
      d[e] = wb32[(size_t)idx[e] * (NB / 2)];     // 40 loads in flight

    unsigned short* rp0 = lsA + (2 * lane) * 168 + wv * 40;   // row 2l
    unsigned short* rp1 = rp0 + 168;                          // row 2l+1

#define PKLO(a, b) (((a) & 0xFFFFu) | ((b) << 16))
#define PKHI(a, b) (((a) >> 16) | ((b) & 0xFFFF0000u))
#pragma unroll
    for (int k = 0; k < 5; k++) {
      uint4 lo = {PKLO(d[8*k+0], d[8*k+1]), PKLO(d[8*k+2], d[8*k+3]),
                  PKLO(d[8*k+4], d[8*k+5]), PKLO(d[8*k+6], d[8*k+7])};
      uint4 hi = {PKHI(d[8*k+0], d[8*k+1]), PKHI(d[8*k+2], d[8*k+3]),
                  PKHI(d[8*k+4], d[8*k+5]), PKHI(d[8*k+6], d[8*k+7])};
      *(uint4*)(rp0 + k * 8) = lo;
      *(uint4*)(rp1 + k * 8) = hi;
    }
#undef PKLO
#undef PKHI
  }

  const unsigned short* bbase = Bf + (size_t)f * 20480 + lane * 8;

  // ---- double-buffered B fragments: explicitly named (rule #20 safe) ----
  short8 bA0, bA1, bA2, bA3, bA4, bA5, bA6, bA7;
  short8 bB0, bB1, bB2, bB3, bB4, bB5, bB6, bB7;

#define G1_LOAD(P, kcc) \
  P##0 = *(const short8*)(bbase + 0*2560 + (kcc)*512); \
  P##1 = *(const short8*)(bbase + 1*2560 + (kcc)*512); \
  P##2 = *(const short8*)(bbase + 2*2560 + (kcc)*512); \
  P##3 = *(const short8*)(bbase + 3*2560 + (kcc)*512); \
  P##4 = *(const short8*)(bbase + 4*2560 + (kcc)*512); \
  P##5 = *(const short8*)(bbase + 5*2560 + (kcc)*512); \
  P##6 = *(const short8*)(bbase + 6*2560 + (kcc)*512); \
  P##7 = *(const short8*)(bbase + 7*2560 + (kcc)*512);

  // prefetch kc=0 before the barrier (independent of gather)
  G1_LOAD(bA, 0)

  __syncthreads();                     // the ONLY barrier

  // ---- GEMM1: (exp-ws)[128x160] @ Ep[160x128], B double-buffered ----
  //      + ones-column MFMA computing the softmax denominators
  const unsigned short* pa0 = lsA + (wv * 16 + c) * 168 + q * 8;
  const unsigned short* pa1 = pa0 + 64 * 168;
  const short onev = (c == 0) ? (short)0x3F80 : (short)0;  // bf16 1.0 in col 0
  short8 bones;
#pragma unroll
  for (int j = 0; j < 8; j++) bones[j] = onev;

  floatx4 acc0[8], acc1[8];
#pragma unroll
  for (int n = 0; n < 8; n++) {
    acc0[n] = (floatx4){0.f, 0.f, 0.f, 0.f};
    acc1[n] = (floatx4){0.f, 0.f, 0.f, 0.f};
  }
  floatx4 accs0 = (floatx4){0.f, 0.f, 0.f, 0.f};
  floatx4 accs1 = (floatx4){0.f, 0.f, 0.f, 0.f};

#define G1_MFMA(P, kcc) \
  { short8 a0 = *(const short8*)(pa0 + (kcc)*32); \
    short8 a1 = *(const short8*)(pa1 + (kcc)*32); \
    acc0[0] = __builtin_amdgcn_mfma_f32_16x16x32_bf16(a0, P##0, acc0[0],0,0,0); \
    acc1[0] = __builtin_amdgcn_mfma_f32_16x16x32_bf16(a1, P##0, acc1[0],0,0,0); \
    acc0[1] = __builtin_amdgcn_mfma_f32_16x16x32_bf16(a0, P##1, acc0[1],0,0,0); \
    acc1[1] = __builtin_amdgcn_mfma_f32_16x16x32_bf16(a1, P##1, acc1[1],0,0,0); \
    acc0[2] = __builtin_amdgcn_mfma_f32_16x16x32_bf16(a0, P##2, acc0[2],0,0,0); \
    acc1[2] = __builtin_amdgcn_mfma_f32_16x16x32_bf16(a1, P##2, acc1[2],0,0,0); \
    acc0[3] = __builtin_amdgcn_mfma_f32_16x16x32_bf16(a0, P##3, acc0[3],0,0,0); \
    acc1[3] = __builtin_amdgcn_mfma_f32_16x16x32_bf16(a1, P##3, acc1[3],0,0,0); \
    acc0[4] = __builtin_amdgcn_mfma_f32_16x16x32_bf16(a0, P##4, acc0[4],0,0,0); \
    acc1[4] = __builtin_amdgcn_mfma_f32_16x16x32_bf16(a1, P##4, acc1[4],0,0,0); \
    acc0[5] = __builtin_amdgcn_mfma_f32_16x16x32_bf16(a0, P##5, acc0[5],0,0,0); \
    acc1[5] = __builtin_amdgcn_mfma_f32_16x16x32_bf16(a1, P##5, acc1[5],0,0,0); \
    acc0[6] = __builtin_amdgcn_mfma_f32_16x16x32_bf16(a0, P##6, acc0[6],0,0,0); \
    acc1[6] = __builtin_amdgcn_mfma_f32_16x16x32_bf16(a1, P##6, acc1[6],0,0,0); \
    acc0[7] = __builtin_amdgcn_mfma_f32_16x16x32_bf16(a0, P##7, acc0[7],0,0,0); \
    acc1[7] = __builtin_amdgcn_mfma_f32_16x16x32_bf16(a1, P##7, acc1[7],0,0,0); \
    accs0   = __builtin_amdgcn_mfma_f32_16x16x32_bf16(a0, bones, accs0,0,0,0); \
    accs1   = __builtin_amdgcn_mfma_f32_16x16x32_bf16(a1, bones, accs1,0,0,0); }

  __builtin_amdgcn_s_setprio(1);
  G1_LOAD(bB, 1)   // prefetch kc1 under kc0's MFMAs
  G1_MFMA(bA, 0)
  G1_LOAD(bA, 2)
  G1_MFMA(bB, 1)
  G1_LOAD(bB, 3)
  G1_MFMA(bA, 2)
  G1_LOAD(bA, 4)
  G1_MFMA(bB, 3)
  G1_MFMA(bA, 4)
  __builtin_amdgcn_s_setprio(0);
#undef G1_MFMA
#undef G1_LOAD

  // ---- LN1 (both tiles): LN(x/s) == (x-mu)*rsqrt(var + eps*s^2) ----
  {
    float lw[8], lb[8];
#pragma unroll
    for (int n = 0; n < 8; n++) { lw[n] = ln1w[n * 16 + c]; lb[n] = ln1b[n * 16 + c]; }
#pragma unroll
    for (int rr = 0; rr < 4; rr++) {
      {
        float st = bcast16(accs0[rr]);         // denominator, row q*4+rr (t0)
        float s1 = 0.f, s2 = 0.f;
#pragma unroll
        for (int n = 0; n < 8; n++) { float v = acc0[n][rr]; s1 += v; s2 += v * v; }
        s1 = rowsum16(s1);
        s2 = rowsum16(s2);
        float mu = s1 * (1.f / 128.f);
        float var = fmaxf(s2 * (1.f / 128.f) - mu * mu, 0.f);
        float rs = rsqrtf(var + GEPS * st * st);
#pragma unroll
        for (int n = 0; n < 8; n++)
          acc0[n][rr] = (acc0[n][rr] - mu) * rs * lw[n] + lb[n];
      }
      {
        float st = bcast16(accs1[rr]);         // denominator, row q*4+rr (t1)
        float s1 = 0.f, s2 = 0.f;
#pragma unroll
        for (int n = 0; n < 8; n++) { float v = acc1[n][rr]; s1 += v; s2 += v * v; }
        s1 = rowsum16(s1);
        s2 = rowsum16(s2);
        float mu = s1 * (1.f / 128.f);
        float var = fmaxf(s2 * (1.f / 128.f) - mu * mu, 0.f);
        float rs = rsqrtf(var + GEPS * st * st);
#pragma unroll
        for (int n = 0; n < 8; n++)
          acc1[n][rr] = (acc1[n][rr] - mu) * rs * lw[n] + lb[n];
      }
    }
  }

  // ---- Fn -> lsA (A-layout bf16, wave-private rows; no barrier needed) ----
#pragma unroll
  for (int rr = 0; rr < 4; rr++)
#pragma unroll
    for (int n = 0; n < 8; n++) {
      lsA[(wv * 16 + q * 4 + rr) * 168 + n * 16 + c] =
          (unsigned short)f2bfu(acc0[n][rr]);
      lsA[(64 + wv * 16 + q * 4 + rr) * 168 + n * 16 + c] =
          (unsigned short)f2bfu(acc1[n][rr]);
    }

  // ---- GEMM2: H = Fn[128x128] @ fc1w[128x128], W1f double-buffered ----
  {
    short8 a00 = *(const short8*)(pa0);
    short8 a01 = *(const short8*)(pa0 + 32);
    short8 a02 = *(const short8*)(pa0 + 64);
    short8 a03 = *(const short8*)(pa0 + 96);
    short8 a10 = *(const short8*)(pa1);
    short8 a11 = *(const short8*)(pa1 + 32);
    short8 a12 = *(const short8*)(pa1 + 64);
    short8 a13 = *(const short8*)(pa1 + 96);
    const unsigned short* w1p = W1f + lane * 8;

#define G2_LOAD(P, nn) \
    P##0 = *(const short8*)(w1p + (nn)*2048); \
    P##1 = *(const short8*)(w1p + (nn)*2048 + 512); \
    P##2 = *(const short8*)(w1p + (nn)*2048 + 1024); \
    P##3 = *(const short8*)(w1p + (nn)*2048 + 1536);

#define G2_MFMA(P, nn) \
    { floatx4 t0 = __builtin_amdgcn_mfma_f32_16x16x32_bf16(a00, P##0, (floatx4){0.f,0.f,0.f,0.f},0,0,0); \
      t0 = __builtin_amdgcn_mfma_f32_16x16x32_bf16(a01, P##1, t0,0,0,0); \
      t0 = __builtin_amdgcn_mfma_f32_16x16x32_bf16(a02, P##2, t0,0,0,0); \
      t0 = __builtin_amdgcn_mfma_f32_16x16x32_bf16(a03, P##3, t0,0,0,0); \
      floatx4 t1 = __builtin_amdgcn_mfma_f32_16x16x32_bf16(a10, P##0, (floatx4){0.f,0.f,0.f,0.f},0,0,0); \
      t1 = __builtin_amdgcn_mfma_f32_16x16x32_bf16(a11, P##1, t1,0,0,0); \
      t1 = __builtin_amdgcn_mfma_f32_16x16x32_bf16(a12, P##2, t1,0,0,0); \
      t1 = __builtin_amdgcn_mfma_f32_16x16x32_bf16(a13, P##3, t1,0,0,0); \
      acc0[nn] = t0; \
      acc1[nn] = t1; }

    __builtin_amdgcn_s_setprio(1);
    G2_LOAD(bA, 0)
    G2_LOAD(bB, 1)
    G2_MFMA(bA, 0)
    G2_LOAD(bA, 2)
    G2_MFMA(bB, 1)
    G2_LOAD(bB, 3)
    G2_MFMA(bA, 2)
    G2_LOAD(bA, 4)
    G2_MFMA(bB, 3)
    G2_LOAD(bB, 5)
    G2_MFMA(bA, 4)
    G2_LOAD(bA, 6)
    G2_MFMA(bB, 5)
    G2_LOAD(bB, 7)
    G2_MFMA(bA, 6)
    G2_MFMA(bB, 7)
    __builtin_amdgcn_s_setprio(0);
#undef G2_MFMA
#undef G2_LOAD
  }

  // ---- bias + ReLU + LN2 (both tiles, DPP row-reduce) ----
  {
    float fb[8], lw[8], lb[8];
#pragma unroll
    for (int n = 0; n < 8; n++) {
      fb[n] = fc1b[n * 16 + c];
      lw[n] = ln2w[n * 16 + c]; lb[n] = ln2b[n * 16 + c];
    }
#pragma unroll
    for (int rr = 0; rr < 4; rr++) {
      {
#pragma unroll
        for (int n = 0; n < 8; n++) acc0[n][rr] = fmaxf(acc0[n][rr] + fb[n], 0.f);
        float s1 = 0.f, s2 = 0.f;
#pragma unroll
        for (int n = 0; n < 8; n++) { float v = acc0[n][rr]; s1 += v; s2 += v * v; }
        s1 = rowsum16(s1);
        s2 = rowsum16(s2);
        float mu = s1 * (1.f / 128.f);
        float var = fmaxf(s2 * (1.f / 128.f) - mu * mu, 0.f);
        float rs = rsqrtf(var + GEPS);
#pragma unroll
        for (int n = 0; n < 8; n++)
          acc0[n][rr] = (acc0[n][rr] - mu) * rs * lw[n] + lb[n];
      }
      {
#pragma unroll
        for (int n = 0; n < 8; n++) acc1[n][rr] = fmaxf(acc1[n][rr] + fb[n], 0.f);
        float s1 = 0.f, s2 = 0.f;
#pragma unroll
        for (int n = 0; n < 8; n++) { float v = acc1[n][rr]; s1 += v; s2 += v * v; }
        s1 = rowsum16(s1);
        s2 = rowsum16(s2);
        float mu = s1 * (1.f / 128.f);
        float var = fmaxf(s2 * (1.f / 128.f) - mu * mu, 0.f);
        float rs = rsqrtf(var + GEPS);
#pragma unroll
        for (int n = 0; n < 8; n++)
          acc1[n][rr] = (acc1[n][rr] - mu) * rs * lw[n] + lb[n];
      }
    }
  }

  // ---- H2 -> lsA (A-layout, wave-private rows; no barrier) ----
#pragma unroll
  for (int rr = 0; rr < 4; rr++)
#pragma unroll
    for (int n = 0; n < 8; n++) {
      lsA[(wv * 16 + q * 4 + rr) * 168 + n * 16 + c] =
          (unsigned short)f2bfu(acc0[n][rr]);
      lsA[(64 + wv * 16 + q * 4 + rr) * 168 + n * 16 + c] =
          (unsigned short)f2bfu(acc1[n][rr]);
    }

  // ---- fc2 (16-col padded tile), W2f loaded once per 2 tiles ----
  floatx4 o40 = (floatx4){0.f, 0.f, 0.f, 0.f};
  floatx4 o41 = (floatx4){0.f, 0.f, 0.f, 0.f};
#pragma unroll
  for (int kc = 0; kc < 4; kc++) {
    short8 a0 = *(const short8*)(pa0 + kc * 32);
    short8 a1 = *(const short8*)(pa1 + kc * 32);
    short8 b = *(const short8*)(W2f + kc * 512 + lane * 8);
    o40 = __builtin_amdgcn_mfma_f32_16x16x32_bf16(a0, b, o40, 0, 0, 0);
    o41 = __builtin_amdgcn_mfma_f32_16x16x32_bf16(a1, b, o41, 0, 0, 0);
  }
  if (c < NCLS) {
    float bias = fc2b[c];
#pragma unroll
    for (int rr = 0; rr < 4; rr++) {
      atomicAdd(out + (size_t)(b0 + wv * 16 + q * 4 + rr) * NCLS + c,
                (o40[rr] + bias) * 0.01f);
      atomicAdd(out + (size_t)(b0 + 64 + wv * 16 + q * 4 + rr) * NCLS + c,
                (o41[rr] + bias) * 0.01f);
    }
  }
}

// ---------------------------------------------------------------------------
extern "C" void kernel_launch(void* const* d_in, const int* in_sizes, int n_in,
                              void* d_out, int out_size, void* d_ws, size_t ws_size,
                              hipStream_t stream)
{
  (void)in_sizes; (void)n_in; (void)ws_size; (void)out_size;
  const float* x    = (const float*)d_in[0];
  const float* w1   = (const float*)d_in[1];
  const float* b1   = (const float*)d_in[2];
  const int*   perm = (const int*)d_in[3];
  const float* gn1w = (const float*)d_in[4];
  const float* gn1b = (const float*)d_in[5];
  const float* c2w  = (const float*)d_in[6];
  const float* c2b  = (const float*)d_in[7];
  const float* gn2w = (const float*)d_in[8];
  const float* gn2b = (const float*)d_in[9];
  const float* c3w  = (const float*)d_in[10];
  const float* c3b  = (const float*)d_in[11];
  const int*   swr  = (const int*)d_in[12];
  const float* E    = (const float*)d_in[13];
  const float* ln1w = (const float*)d_in[14];
  const float* ln1b = (const float*)d_in[15];
  const float* fc1w = (const float*)d_in[16];
  const float* fc1b = (const float*)d_in[17];
  const float* ln2w = (const float*)d_in[18];
  const float* ln2b = (const float*)d_in[19];
  const float* fc2w = (const float*)d_in[20];
  const float* fc2b = (const float*)d_in[21];
  float* out = (float*)d_out;

  // workspace layout:
  //   [0, 13.1MB)       : wT exp-logits bf16 [1600][B]
  //   [13.1MB, +4.10MB) : Bf (100*20480 shorts)
  //   then W1f 32,768 B, W2f 4,096 B
  const size_t W_BYTES = (size_t)NB * NRODT * 2;     // 13,107,200
  unsigned short* wTbuf = (unsigned short*)d_ws;
  unsigned short* Bfb   = (unsigned short*)((char*)d_ws + W_BYTES);
  unsigned short* W1fb  = (unsigned short*)((char*)d_ws + W_BYTES + 4096000);
  unsigned short* W2fb  = (unsigned short*)((char*)d_ws + W_BYTES + 4096000 + 32768);

  k01_prep<<<3200 + NFOR + 2 + 3, 256, 0, stream>>>(
      x, w1, b1, perm, gn1w, gn1b, c2w, c2b, gn2w, gn2b, c3w, c3b,
      E, swr, fc1w, fc2w, wTbuf, Bfb, W1fb, W2fb, out);
  dim3 g3(NB / 128, NFOR);
  k3_mfma<<<g3, 256, 0, stream>>>(wTbuf, swr, Bfb, W1fb, W2fb,
                                  ln1w, ln1b, fc1b, ln2w, ln2b, fc2b, out);
}